// Round 17
// baseline (161.878 us; speedup 1.0000x reference)
//
#include <hip/hip_runtime.h>
#include <hip/hip_bf16.h>
#include <cstdint>

// Problem constants: B=2, N=2048, C=1024, H=16, D=64
// Q is stored pre-scaled by D^-0.5 * log2(e) so softmax runs in exp2 domain.
// V is materialized TRANSPOSED in global memory (VtG[bh][d][n]) by the QKV GEMM.
// STATIC-MAX softmax: rms_norm bounds |S'| <= 8*log2e = 11.54 < 12, so P = exp2(S' - 12).
// Attention is KV-SPLIT into 2 independent half-KV passes (separate blocks -> 4 blocks/CU
// = 4 waves/SIMD, fixing the 2-wave latency-idle) + a light merge kernel (no m-merge
// needed: both halves share the static max).
#define RMS_EPS 1.1920928955078125e-07f
#define SMAX 12.0f

typedef __bf16 bf16;
typedef __attribute__((ext_vector_type(8))) __bf16 bf16x8;
typedef __attribute__((ext_vector_type(4))) __bf16 bf16x4;
typedef __attribute__((ext_vector_type(4))) float f32x4;
typedef __attribute__((ext_vector_type(16))) float f32x16;
typedef unsigned int u32;
typedef __attribute__((ext_vector_type(4))) u32 u32x4;

__device__ __forceinline__ void gload16(const bf16* g, bf16* l) {
  __builtin_amdgcn_global_load_lds(
      (__attribute__((address_space(1))) void*)(g),
      (__attribute__((address_space(3))) void*)(l), 16, 0, 0);
}

__device__ __forceinline__ float fexp2(float x) {
#if __has_builtin(__builtin_amdgcn_exp2f)
  return __builtin_amdgcn_exp2f(x);
#else
  return exp2f(x);
#endif
}

__device__ __forceinline__ u32 pack2(float a, float b) {
  unsigned short xa = __builtin_bit_cast(unsigned short, (bf16)a);
  unsigned short xb = __builtin_bit_cast(unsigned short, (bf16)b);
  return (u32)xa | ((u32)xb << 16);
}

// ---------------- fused f32 -> bf16 convert for all three inputs ----------------
__global__ __launch_bounds__(256) void cvt3_kernel(
    const float* __restrict__ x, const float* __restrict__ wq, const float* __restrict__ wp,
    bf16* __restrict__ xo, bf16* __restrict__ wqo, bf16* __restrict__ wpo) {
  int i = blockIdx.x * 256 + threadIdx.x;
  const float* s; bf16* d; int off;
  if (i < 524288) { s = x; d = xo; off = i; }
  else if (i < 917504) { s = wq; d = wqo; off = i - 524288; }
  else { s = wp; d = wpo; off = i - 917504; }
  const float4* s4 = (const float4*)s;
  float4 a = s4[off * 2], b = s4[off * 2 + 1];
  bf16x8 o;
  o[0] = (bf16)a.x; o[1] = (bf16)a.y; o[2] = (bf16)a.z; o[3] = (bf16)a.w;
  o[4] = (bf16)b.x; o[5] = (bf16)b.y; o[6] = (bf16)b.z; o[7] = (bf16)b.w;
  *(bf16x8*)(d + off * 8) = o;
}

// ---------------- GEMM C = A * B^T (R16, proven) ----------------
template <int MODE, int MINW>
__global__ __launch_bounds__(256, MINW) void gemm_bt(
    const bf16* __restrict__ A, const bf16* __restrict__ B,
    float* __restrict__ Cout, int Ncols,
    bf16* __restrict__ Qb, bf16* __restrict__ Kb, bf16* __restrict__ VtG,
    float* __restrict__ vninv) {
  union ShG {
    struct { bf16 As[128 * 64]; bf16 Bs[128 * 64]; } s;
    bf16 T[128 * 136];
  };
  __shared__ ShG shg;
  bf16* As = shg.s.As;
  bf16* Bs = shg.s.Bs;

  const int tid = threadIdx.x;
  const int wave = tid >> 6, lane = tid & 63;
  const int l15 = lane & 15, g = lane >> 4;
  const int nwg = gridDim.x * gridDim.y;
  const int wg0 = blockIdx.y * gridDim.x + blockIdx.x;
  const int wg = (wg0 & 7) * (nwg >> 3) + (wg0 >> 3);
  const int m0 = (wg / gridDim.x) * 128, n0 = (wg % gridDim.x) * 128;
  const int wr = wave >> 1, wc = wave & 1;

  f32x4 acc[4][4] = {};

  for (int k0 = 0; k0 < 1024; k0 += 64) {
    __syncthreads();
#pragma unroll
    for (int i = 0; i < 4; ++i) {
      const int gid = (i * 4 + wave) * 64 + lane;
      const int row = gid >> 3, gk = gid & 7;
      const int srcoff = k0 + ((gk ^ (row & 7)) << 3);
      gload16(A + (m0 + row) * 1024 + srcoff, As + (i * 4 + wave) * 512);
      gload16(B + (n0 + row) * 1024 + srcoff, Bs + (i * 4 + wave) * 512);
    }
    __syncthreads();
#pragma unroll
    for (int kc = 0; kc < 2; ++kc) {
      bf16x8 af[4], bfb[4];
#pragma unroll
      for (int mi = 0; mi < 4; ++mi) {
        const int row = wr * 64 + mi * 16 + l15;
        af[mi] = *(const bf16x8*)&As[row * 64 + (((kc * 4 + g) ^ (l15 & 7)) << 3)];
      }
#pragma unroll
      for (int ni = 0; ni < 4; ++ni) {
        const int row = wc * 64 + ni * 16 + l15;
        bfb[ni] = *(const bf16x8*)&Bs[row * 64 + (((kc * 4 + g) ^ (l15 & 7)) << 3)];
      }
#pragma unroll
      for (int mi = 0; mi < 4; ++mi)
#pragma unroll
        for (int ni = 0; ni < 4; ++ni)
          acc[mi][ni] = __builtin_amdgcn_mfma_f32_16x16x32_bf16(af[mi], bfb[ni], acc[mi][ni], 0, 0, 0);
    }
  }

  if (MODE == 0) {
#pragma unroll
    for (int mi = 0; mi < 4; ++mi) {
      const int mrow = m0 + wr * 64 + mi * 16 + g * 4;
#pragma unroll
      for (int r = 0; r < 4; ++r) {
        float* cp = Cout + (long)(mrow + r) * Ncols + n0 + wc * 64 + l15;
#pragma unroll
        for (int ni = 0; ni < 4; ++ni) cp[ni * 16] = acc[mi][ni][r];
      }
    }
  } else {
    const int blk_which = n0 >> 10;
    const int ncol = n0 + wc * 64;
    const int h = (ncol >> 6) & 15;

    if (blk_which == 2) {
#pragma unroll
      for (int mi = 0; mi < 4; ++mi) {
#pragma unroll
        for (int r = 0; r < 4; ++r) {
          float ss = 0.f;
#pragma unroll
          for (int ni = 0; ni < 4; ++ni) ss += acc[mi][ni][r] * acc[mi][ni][r];
          ss += __shfl_xor(ss, 1); ss += __shfl_xor(ss, 2);
          ss += __shfl_xor(ss, 4); ss += __shfl_xor(ss, 8);
          if (l15 == 0) {
            const int m = m0 + wr * 64 + mi * 16 + g * 4 + r;
            const int b = m >> 11, nseq = m & 2047;
            vninv[(b * 16 + h) * 2048 + nseq] = 1.0f / fmaxf(sqrtf(ss), 1e-12f);
          }
        }
      }
      __syncthreads();
#pragma unroll
      for (int mi = 0; mi < 4; ++mi)
#pragma unroll
        for (int ni = 0; ni < 4; ++ni) {
          bf16x4 v4;
#pragma unroll
          for (int r = 0; r < 4; ++r) v4[r] = (bf16)acc[mi][ni][r];
          *(bf16x4*)&shg.T[(wc * 64 + ni * 16 + l15) * 136 + wr * 64 + mi * 16 + g * 4] = v4;
        }
      __syncthreads();
      const int c = tid >> 1, half = tid & 1;
      const int gcol = n0 + c;
      const int hh = (gcol >> 6) & 15, d = gcol & 63;
      const int mb = m0 >> 11, nseq0 = m0 & 2047;
      bf16* dst = VtG + ((long)(mb * 16 + hh) * 64 + d) * 2048 + nseq0 + half * 64;
      const bf16* src = &shg.T[c * 136 + half * 64];
#pragma unroll
      for (int i = 0; i < 8; ++i)
        *(bf16x8*)(dst + i * 8) = *(const bf16x8*)(src + i * 8);
    } else {
      float scv[4][4];
#pragma unroll
      for (int mi = 0; mi < 4; ++mi) {
#pragma unroll
        for (int r = 0; r < 4; ++r) {
          float ss = 0.f;
#pragma unroll
          for (int ni = 0; ni < 4; ++ni) ss += acc[mi][ni][r] * acc[mi][ni][r];
          ss += __shfl_xor(ss, 1); ss += __shfl_xor(ss, 2);
          ss += __shfl_xor(ss, 4); ss += __shfl_xor(ss, 8);
          const float sc = rsqrtf(ss * (1.0f / 64) + RMS_EPS);
          scv[mi][r] = (blk_which == 0) ? sc * (0.125f * 1.44269504088896340736f) : sc;
        }
      }
      __syncthreads();
#pragma unroll
      for (int mi = 0; mi < 4; ++mi)
#pragma unroll
        for (int r = 0; r < 4; ++r) {
          const float sc = scv[mi][r];
#pragma unroll
          for (int ni = 0; ni < 4; ++ni)
            shg.T[(wr * 64 + mi * 16 + g * 4 + r) * 136 + wc * 64 + ni * 16 + l15] =
                (bf16)(acc[mi][ni][r] * sc);
        }
      __syncthreads();
      bf16* QK = (blk_which == 0) ? Qb : Kb;
      const int c8 = tid & 7, chh = (tid >> 3) & 1, r0 = tid >> 4;
      const int hh = ((n0 + chh * 64) >> 6) & 15;
#pragma unroll
      for (int p = 0; p < 8; ++p) {
        const int rr = r0 + p * 16;
        const int m = m0 + rr;
        const int bq = m >> 11, nseq = m & 2047;
        *(bf16x8*)(QK + ((long)(bq * 16 + hh) * 2048 + nseq) * 64 + c8 * 8) =
            *(const bf16x8*)&shg.T[rr * 136 + chh * 64 + c8 * 8];
      }
    }
  }
}

// ---------------- attention KV-split pass: 4 waves x 32x32 MFMA, KVBLK=64 ----------------
// grid: 32 bh * 16 qb * 2 halves = 1024 blocks; 256 threads; 32KB LDS -> 4 blocks/CU
// = 4 waves/SIMD. Each block covers 128 q-rows x 1024 KV rows (half), writing
// UN-NORMALIZED bf16 partial O (Yb-layout) + f32 partial row-sum Lp.
__global__ __launch_bounds__(256, 4) void attn_split_kernel(
    const bf16* __restrict__ Qb, const bf16* __restrict__ Kb, const bf16* __restrict__ VtG,
    bf16* __restrict__ P0, bf16* __restrict__ P1, float* __restrict__ Lp) {
  __shared__ bf16 Ks[2][64 * 64];  // [j][d], swizzle key (j^(j>>3))&7
  __shared__ bf16 Vt[2][64 * 64];  // [d][j], swizzle key (d^(d>>3))&7

  const int tid = threadIdx.x;
  const int wq = tid >> 6;
  const int lane = tid & 63;
  const int l31 = lane & 31, hi = lane >> 5;
  // XCD swizzle (1024 % 8 == 0 -> bijective)
  const int wg = (blockIdx.x & 7) * (gridDim.x >> 3) + (blockIdx.x >> 3);
  const int bh = wg >> 5, qb = (wg >> 1) & 15, half = wg & 1;
  const int b = bh >> 4, h = bh & 15;
  const long off = (long)bh * (2048 * 64);
  const bf16* Qp = Qb + off;
  const bf16* Kp = Kb + off + (long)(half * 1024) * 64;
  const bf16* VtP = VtG + (long)bh * 64 * 2048 + half * 1024;
  const int qrow = qb * 128 + wq * 32 + l31;

  // Q B-frags: row q=l31, k = kc*16 + hi*8 + i
  bf16x8 qf[4];
#pragma unroll
  for (int kc = 0; kc < 4; ++kc)
    qf[kc] = *(const bf16x8*)&Qp[qrow * 64 + kc * 16 + hi * 8];

  f32x16 o[2] = {};   // O^T[d][q]: q=l31, d = (r&3)+8*(r>>2)+4*hi+32*dt
  f32x16 lacc = {};   // per-slot P-sum accumulator

  // staging offsets: 8 chunks of 64 granules; 2 K-gloads + 2 V-gloads per thread
  int koff[2], voff[2];
#pragma unroll
  for (int i = 0; i < 2; ++i) {
    const int chunk = i * 4 + wq;
    const int gid = chunk * 64 + lane;
    const int row = gid >> 3, gk = gid & 7;
    const int key = (row ^ (row >> 3)) & 7;
    koff[i] = row * 64 + ((gk ^ key) << 3);     // K row j, + kv0*64 per tile
    voff[i] = row * 2048 + ((gk ^ key) << 3);   // Vt row d (stride 2048), + kv0 per tile
  }

  // prologue: stage tile 0
#pragma unroll
  for (int i = 0; i < 2; ++i) {
    const int chunk = i * 4 + wq;
    gload16(Kp + koff[i], &Ks[0][chunk * 512]);
    gload16(VtP + voff[i], &Vt[0][chunk * 512]);
  }
  __syncthreads();

  int cur = 0;
  for (int it = 0; it < 16; ++it) {
    const int kv0 = it * 64;
    if (it < 15) {  // async prefetch next tile (T14)
#pragma unroll
      for (int i = 0; i < 2; ++i) {
        const int chunk = i * 4 + wq;
        gload16(Kp + (kv0 + 64) * 64 + koff[i], &Ks[cur ^ 1][chunk * 512]);
        gload16(VtP + (kv0 + 64) + voff[i], &Vt[cur ^ 1][chunk * 512]);
      }
    }
    const bf16* ks = &Ks[cur][0];
    const bf16* vt = &Vt[cur][0];

    // S^T - 12 = K * Q^T + (-12)
    f32x16 sv[2];
#pragma unroll
    for (int jt = 0; jt < 2; ++jt)
#pragma unroll
      for (int r = 0; r < 16; ++r) sv[jt][r] = -SMAX;
    __builtin_amdgcn_s_setprio(1);
#pragma unroll
    for (int jt = 0; jt < 2; ++jt) {
      const int j = jt * 32 + l31;
      const int key = (j ^ (j >> 3)) & 7;
#pragma unroll
      for (int kc = 0; kc < 4; ++kc) {
        bf16x8 kf = *(const bf16x8*)&ks[j * 64 + (((2 * kc + hi) ^ key) << 3)];
        sv[jt] = __builtin_amdgcn_mfma_f32_32x32x16_bf16(kf, qf[kc], sv[jt], 0, 0, 0);
      }
    }
    __builtin_amdgcn_s_setprio(0);

    // P = exp2(S' - 12)
#pragma unroll
    for (int jt = 0; jt < 2; ++jt)
#pragma unroll
      for (int r = 0; r < 16; ++r) sv[jt][r] = fexp2(sv[jt][r]);

#pragma unroll
    for (int r = 0; r < 16; ++r) lacc[r] += sv[0][r] + sv[1][r];

    // P (C-layout, q=lane) -> bf16 B-frags: pack + half-wave exchange (proven mapping)
    u32 w[2][8];
#pragma unroll
    for (int jt = 0; jt < 2; ++jt)
#pragma unroll
      for (int i = 0; i < 8; ++i) w[jt][i] = pack2(sv[jt][2 * i], sv[jt][2 * i + 1]);
    bf16x8 pafr[4];  // B-frag kc: col q=l31, k-local i -> j = kc*16 + hi*8 + i
#pragma unroll
    for (int kc = 0; kc < 4; ++kc) {
      const int c = kc & 1, jt = kc >> 1;
      const u32 z1 = hi ? w[jt][4 * c + 0] : w[jt][4 * c + 2];
      const u32 z2 = hi ? w[jt][4 * c + 1] : w[jt][4 * c + 3];
      const u32 r1 = __shfl_xor(z1, 32);
      const u32 r2 = __shfl_xor(z2, 32);
      u32x4 pv;
      pv[0] = hi ? r1 : w[jt][4 * c + 0];
      pv[1] = hi ? r2 : w[jt][4 * c + 1];
      pv[2] = hi ? w[jt][4 * c + 2] : r1;
      pv[3] = hi ? w[jt][4 * c + 3] : r2;
      pafr[kc] = __builtin_bit_cast(bf16x8, pv);
    }

    // O^T += V^T * P : j-dim 64 (4 kc)
    __builtin_amdgcn_s_setprio(1);
#pragma unroll
    for (int dt = 0; dt < 2; ++dt) {
      const int d = dt * 32 + l31;
      const int key = (d ^ (d >> 3)) & 7;
#pragma unroll
      for (int kc = 0; kc < 4; ++kc) {
        bf16x8 vf = *(const bf16x8*)&vt[d * 64 + (((2 * kc + hi) ^ key) << 3)];
        o[dt] = __builtin_amdgcn_mfma_f32_32x32x16_bf16(vf, pafr[kc], o[dt], 0, 0, 0);
      }
    }
    __builtin_amdgcn_s_setprio(0);

    __syncthreads();
    cur ^= 1;
  }

  // partial row-sum: tree over 16 slots + cross-half
  float sm[16];
#pragma unroll
  for (int r = 0; r < 16; ++r) sm[r] = lacc[r];
#pragma unroll
  for (int s2 = 8; s2 > 0; s2 >>= 1)
#pragma unroll
    for (int r = 0; r < s2; ++r) sm[r] += sm[r + s2];
  const float lpart = sm[0] + __shfl_xor(sm[0], 32);

  // partial stores: un-normalized O as bf16 in Yb-layout; Lp f32
  bf16* P = half ? P1 : P0;
  const long base = ((long)(b * 2048 + qrow)) * 1024 + h * 64;
#pragma unroll
  for (int dt = 0; dt < 2; ++dt)
#pragma unroll
    for (int rr = 0; rr < 4; ++rr)
#pragma unroll
      for (int e = 0; e < 4; ++e) {
        const int r = rr * 4 + e;
        const int d = e + 8 * rr + 4 * hi + 32 * dt;
        P[base + d] = (bf16)o[dt][r];
      }
  if (hi == 0) Lp[half * 65536 + bh * 2048 + qrow] = lpart;
}

// ---------------- merge: y = (O0+O1)/(l0+l1); xsa projection; in-place into Yb ----------
// NOTE: Yb aliases P0 (element-wise in-place; each thread touches only its own 8 elems).
__global__ __launch_bounds__(256) void attn_merge_kernel(
    const bf16* VtG, const float* vninv, const bf16* P1, const float* Lp, bf16* Yb) {
  const int gid = blockIdx.x * 256 + threadIdx.x;  // 0..524287
  const int qg = gid >> 3;                          // bh*2048 + qrow
  const int dseg = gid & 7;
  const int bh = qg >> 11, qrow = qg & 2047;
  const int b = bh >> 4, h = bh & 15;
  const long base = ((long)(b * 2048 + qrow)) * 1024 + h * 64 + dseg * 8;

  const bf16x8 o0 = *(const bf16x8*)(Yb + base);
  const bf16x8 o1 = *(const bf16x8*)(P1 + base);
  const float linv = 1.f / (Lp[qg] + Lp[65536 + qg]);
  const bf16* vp = VtG + (long)bh * 64 * 2048 + qrow;

  float y[8], v[8];
  float t = 0.f;
#pragma unroll
  for (int e = 0; e < 8; ++e) {
    y[e] = ((float)o0[e] + (float)o1[e]) * linv;
    v[e] = (float)vp[(long)(dseg * 8 + e) * 2048];
    t += y[e] * v[e];
  }
  t += __shfl_xor(t, 1); t += __shfl_xor(t, 2); t += __shfl_xor(t, 4);
  const float vni = vninv[qg];
  const float coef = t * vni * vni;
  bf16x8 out;
#pragma unroll
  for (int e = 0; e < 8; ++e) out[e] = (bf16)(y[e] - coef * v[e]);
  *(bf16x8*)(Yb + base) = out;
}

// ---------------- launch ----------------
extern "C" void kernel_launch(void* const* d_in, const int* in_sizes, int n_in,
                              void* d_out, int out_size, void* d_ws, size_t ws_size,
                              hipStream_t stream) {
  (void)in_sizes; (void)n_in; (void)out_size; (void)ws_size;
  const float* x = (const float*)d_in[0];
  const float* w_qkv = (const float*)d_in[1];
  const float* w_proj = (const float*)d_in[2];
  float* out = (float*)d_out;
  char* ws = (char*)d_ws;

  bf16* xb     = (bf16*)(ws);              //  8,388,608  x as bf16 (dead after gemm1 -> P1)
  bf16* wqkvb  = (bf16*)(ws + 8388608);    //  6,291,456  (dead after gemm1 -> Lp)
  bf16* wprojb = (bf16*)(ws + 14680064);   //  2,097,152
  bf16* Qb     = (bf16*)(ws + 16777216);   //  8,388,608  rms-normed * 0.125*log2e
  bf16* Kb     = (bf16*)(ws + 25165824);   //  8,388,608  rms-normed
  bf16* VtG    = (bf16*)(ws + 33554432);   //  8,388,608  (B,H,D,N) V transposed
  float* vninv = (float*)(ws + 41943040);  //    524,288  1/max(||v||,1e-12)
  bf16* Yb     = (bf16*)(ws + 42467328);   //  8,388,608  partial O (split 0) then final Y

  bf16* P1  = xb;                           // split-1 partial O (overlays dead xb)
  float* Lp = (float*)(ws + 8388608);       // [2][65536] f32 (overlays dead wqkvb)

  cvt3_kernel<<<4096, 256, 0, stream>>>(x, w_qkv, w_proj, xb, wqkvb, wprojb);

  gemm_bt<1, 3><<<dim3(24, 32), 256, 0, stream>>>(xb, wqkvb, nullptr, 3072,
                                                  Qb, Kb, VtG, vninv);
  attn_split_kernel<<<1024, 256, 0, stream>>>(Qb, Kb, VtG, Yb, P1, Lp);
  attn_merge_kernel<<<2048, 256, 0, stream>>>(VtG, vninv, P1, Lp, Yb);
  gemm_bt<0, 2><<<dim3(8, 32), 256, 0, stream>>>(Yb, wprojb, out, 1024,
                                                 nullptr, nullptr, nullptr, nullptr);
}

// Round 18
// 159.843 us; speedup vs baseline: 1.0127x; 1.0127x over previous
//
#include <hip/hip_runtime.h>
#include <hip/hip_bf16.h>
#include <cstdint>

// Problem constants: B=2, N=2048, C=1024, H=16, D=64
// Q is stored pre-scaled by D^-0.5 * log2(e) so softmax runs in exp2 domain.
// V is materialized TRANSPOSED in global memory (VtG[bh][d][n]) by the QKV GEMM.
// STATIC-MAX softmax: rms_norm bounds |S'| <= 8*log2e = 11.54 < 12, so P = exp2(S' - 12).
// Attention is KV-SPLIT into 2 half-KV passes (1024 blocks -> 4 blocks/CU = 4 waves/SIMD).
// Partials are stored in [bh][d][n] layout (lane = n -> coalesced), merged by a
// tile-based kernel that also applies the xsa projection.
#define RMS_EPS 1.1920928955078125e-07f
#define SMAX 12.0f

typedef __bf16 bf16;
typedef __attribute__((ext_vector_type(8))) __bf16 bf16x8;
typedef __attribute__((ext_vector_type(4))) __bf16 bf16x4;
typedef __attribute__((ext_vector_type(4))) float f32x4;
typedef __attribute__((ext_vector_type(16))) float f32x16;
typedef unsigned int u32;
typedef __attribute__((ext_vector_type(4))) u32 u32x4;

__device__ __forceinline__ void gload16(const bf16* g, bf16* l) {
  __builtin_amdgcn_global_load_lds(
      (__attribute__((address_space(1))) void*)(g),
      (__attribute__((address_space(3))) void*)(l), 16, 0, 0);
}

__device__ __forceinline__ float fexp2(float x) {
#if __has_builtin(__builtin_amdgcn_exp2f)
  return __builtin_amdgcn_exp2f(x);
#else
  return exp2f(x);
#endif
}

__device__ __forceinline__ u32 pack2(float a, float b) {
  unsigned short xa = __builtin_bit_cast(unsigned short, (bf16)a);
  unsigned short xb = __builtin_bit_cast(unsigned short, (bf16)b);
  return (u32)xa | ((u32)xb << 16);
}

// ---------------- fused f32 -> bf16 convert for all three inputs ----------------
__global__ __launch_bounds__(256) void cvt3_kernel(
    const float* __restrict__ x, const float* __restrict__ wq, const float* __restrict__ wp,
    bf16* __restrict__ xo, bf16* __restrict__ wqo, bf16* __restrict__ wpo) {
  int i = blockIdx.x * 256 + threadIdx.x;
  const float* s; bf16* d; int off;
  if (i < 524288) { s = x; d = xo; off = i; }
  else if (i < 917504) { s = wq; d = wqo; off = i - 524288; }
  else { s = wp; d = wpo; off = i - 917504; }
  const float4* s4 = (const float4*)s;
  float4 a = s4[off * 2], b = s4[off * 2 + 1];
  bf16x8 o;
  o[0] = (bf16)a.x; o[1] = (bf16)a.y; o[2] = (bf16)a.z; o[3] = (bf16)a.w;
  o[4] = (bf16)b.x; o[5] = (bf16)b.y; o[6] = (bf16)b.z; o[7] = (bf16)b.w;
  *(bf16x8*)(d + off * 8) = o;
}

// ---------------- GEMM C = A * B^T (R16, proven) ----------------
template <int MODE, int MINW>
__global__ __launch_bounds__(256, MINW) void gemm_bt(
    const bf16* __restrict__ A, const bf16* __restrict__ B,
    float* __restrict__ Cout, int Ncols,
    bf16* __restrict__ Qb, bf16* __restrict__ Kb, bf16* __restrict__ VtG,
    float* __restrict__ vninv) {
  union ShG {
    struct { bf16 As[128 * 64]; bf16 Bs[128 * 64]; } s;
    bf16 T[128 * 136];
  };
  __shared__ ShG shg;
  bf16* As = shg.s.As;
  bf16* Bs = shg.s.Bs;

  const int tid = threadIdx.x;
  const int wave = tid >> 6, lane = tid & 63;
  const int l15 = lane & 15, g = lane >> 4;
  const int nwg = gridDim.x * gridDim.y;
  const int wg0 = blockIdx.y * gridDim.x + blockIdx.x;
  const int wg = (wg0 & 7) * (nwg >> 3) + (wg0 >> 3);
  const int m0 = (wg / gridDim.x) * 128, n0 = (wg % gridDim.x) * 128;
  const int wr = wave >> 1, wc = wave & 1;

  f32x4 acc[4][4] = {};

  for (int k0 = 0; k0 < 1024; k0 += 64) {
    __syncthreads();
#pragma unroll
    for (int i = 0; i < 4; ++i) {
      const int gid = (i * 4 + wave) * 64 + lane;
      const int row = gid >> 3, gk = gid & 7;
      const int srcoff = k0 + ((gk ^ (row & 7)) << 3);
      gload16(A + (m0 + row) * 1024 + srcoff, As + (i * 4 + wave) * 512);
      gload16(B + (n0 + row) * 1024 + srcoff, Bs + (i * 4 + wave) * 512);
    }
    __syncthreads();
#pragma unroll
    for (int kc = 0; kc < 2; ++kc) {
      bf16x8 af[4], bfb[4];
#pragma unroll
      for (int mi = 0; mi < 4; ++mi) {
        const int row = wr * 64 + mi * 16 + l15;
        af[mi] = *(const bf16x8*)&As[row * 64 + (((kc * 4 + g) ^ (l15 & 7)) << 3)];
      }
#pragma unroll
      for (int ni = 0; ni < 4; ++ni) {
        const int row = wc * 64 + ni * 16 + l15;
        bfb[ni] = *(const bf16x8*)&Bs[row * 64 + (((kc * 4 + g) ^ (l15 & 7)) << 3)];
      }
#pragma unroll
      for (int mi = 0; mi < 4; ++mi)
#pragma unroll
        for (int ni = 0; ni < 4; ++ni)
          acc[mi][ni] = __builtin_amdgcn_mfma_f32_16x16x32_bf16(af[mi], bfb[ni], acc[mi][ni], 0, 0, 0);
    }
  }

  if (MODE == 0) {
#pragma unroll
    for (int mi = 0; mi < 4; ++mi) {
      const int mrow = m0 + wr * 64 + mi * 16 + g * 4;
#pragma unroll
      for (int r = 0; r < 4; ++r) {
        float* cp = Cout + (long)(mrow + r) * Ncols + n0 + wc * 64 + l15;
#pragma unroll
        for (int ni = 0; ni < 4; ++ni) cp[ni * 16] = acc[mi][ni][r];
      }
    }
  } else {
    const int blk_which = n0 >> 10;
    const int ncol = n0 + wc * 64;
    const int h = (ncol >> 6) & 15;

    if (blk_which == 2) {
#pragma unroll
      for (int mi = 0; mi < 4; ++mi) {
#pragma unroll
        for (int r = 0; r < 4; ++r) {
          float ss = 0.f;
#pragma unroll
          for (int ni = 0; ni < 4; ++ni) ss += acc[mi][ni][r] * acc[mi][ni][r];
          ss += __shfl_xor(ss, 1); ss += __shfl_xor(ss, 2);
          ss += __shfl_xor(ss, 4); ss += __shfl_xor(ss, 8);
          if (l15 == 0) {
            const int m = m0 + wr * 64 + mi * 16 + g * 4 + r;
            const int b = m >> 11, nseq = m & 2047;
            vninv[(b * 16 + h) * 2048 + nseq] = 1.0f / fmaxf(sqrtf(ss), 1e-12f);
          }
        }
      }
      __syncthreads();
#pragma unroll
      for (int mi = 0; mi < 4; ++mi)
#pragma unroll
        for (int ni = 0; ni < 4; ++ni) {
          bf16x4 v4;
#pragma unroll
          for (int r = 0; r < 4; ++r) v4[r] = (bf16)acc[mi][ni][r];
          *(bf16x4*)&shg.T[(wc * 64 + ni * 16 + l15) * 136 + wr * 64 + mi * 16 + g * 4] = v4;
        }
      __syncthreads();
      const int c = tid >> 1, half = tid & 1;
      const int gcol = n0 + c;
      const int hh = (gcol >> 6) & 15, d = gcol & 63;
      const int mb = m0 >> 11, nseq0 = m0 & 2047;
      bf16* dst = VtG + ((long)(mb * 16 + hh) * 64 + d) * 2048 + nseq0 + half * 64;
      const bf16* src = &shg.T[c * 136 + half * 64];
#pragma unroll
      for (int i = 0; i < 8; ++i)
        *(bf16x8*)(dst + i * 8) = *(const bf16x8*)(src + i * 8);
    } else {
      float scv[4][4];
#pragma unroll
      for (int mi = 0; mi < 4; ++mi) {
#pragma unroll
        for (int r = 0; r < 4; ++r) {
          float ss = 0.f;
#pragma unroll
          for (int ni = 0; ni < 4; ++ni) ss += acc[mi][ni][r] * acc[mi][ni][r];
          ss += __shfl_xor(ss, 1); ss += __shfl_xor(ss, 2);
          ss += __shfl_xor(ss, 4); ss += __shfl_xor(ss, 8);
          const float sc = rsqrtf(ss * (1.0f / 64) + RMS_EPS);
          scv[mi][r] = (blk_which == 0) ? sc * (0.125f * 1.44269504088896340736f) : sc;
        }
      }
      __syncthreads();
#pragma unroll
      for (int mi = 0; mi < 4; ++mi)
#pragma unroll
        for (int r = 0; r < 4; ++r) {
          const float sc = scv[mi][r];
#pragma unroll
          for (int ni = 0; ni < 4; ++ni)
            shg.T[(wr * 64 + mi * 16 + g * 4 + r) * 136 + wc * 64 + ni * 16 + l15] =
                (bf16)(acc[mi][ni][r] * sc);
        }
      __syncthreads();
      bf16* QK = (blk_which == 0) ? Qb : Kb;
      const int c8 = tid & 7, chh = (tid >> 3) & 1, r0 = tid >> 4;
      const int hh = ((n0 + chh * 64) >> 6) & 15;
#pragma unroll
      for (int p = 0; p < 8; ++p) {
        const int rr = r0 + p * 16;
        const int m = m0 + rr;
        const int bq = m >> 11, nseq = m & 2047;
        *(bf16x8*)(QK + ((long)(bq * 16 + hh) * 2048 + nseq) * 64 + c8 * 8) =
            *(const bf16x8*)&shg.T[rr * 136 + chh * 64 + c8 * 8];
      }
    }
  }
}

// ---------------- attention KV-split pass: 4 waves x 32x32 MFMA, KVBLK=64 ----------------
// grid: 32 bh * 16 qb * 2 halves = 1024 blocks; 256 threads; 32KB LDS -> 4 blocks/CU.
// Partial O stored in [bh][d][n] layout: lane = n -> every store = two 64B runs (coalesced).
__global__ __launch_bounds__(256, 4) void attn_split_kernel(
    const bf16* __restrict__ Qb, const bf16* __restrict__ Kb, const bf16* __restrict__ VtG,
    bf16* __restrict__ P0, bf16* __restrict__ P1, float* __restrict__ Lp) {
  __shared__ bf16 Ks[2][64 * 64];  // [j][d], swizzle key (j^(j>>3))&7
  __shared__ bf16 Vt[2][64 * 64];  // [d][j], swizzle key (d^(d>>3))&7

  const int tid = threadIdx.x;
  const int wq = tid >> 6;
  const int lane = tid & 63;
  const int l31 = lane & 31, hi = lane >> 5;
  // XCD swizzle (1024 % 8 == 0 -> bijective)
  const int wg = (blockIdx.x & 7) * (gridDim.x >> 3) + (blockIdx.x >> 3);
  const int bh = wg >> 5, qb = (wg >> 1) & 15, half = wg & 1;
  const long off = (long)bh * (2048 * 64);
  const bf16* Qp = Qb + off;
  const bf16* Kp = Kb + off + (long)(half * 1024) * 64;
  const bf16* VtP = VtG + (long)bh * 64 * 2048 + half * 1024;
  const int qrow = qb * 128 + wq * 32 + l31;

  // Q B-frags: row q=l31, k = kc*16 + hi*8 + i
  bf16x8 qf[4];
#pragma unroll
  for (int kc = 0; kc < 4; ++kc)
    qf[kc] = *(const bf16x8*)&Qp[qrow * 64 + kc * 16 + hi * 8];

  f32x16 o[2] = {};   // O^T[d][q]: q=l31, d = (r&3)+8*(r>>2)+4*hi+32*dt
  f32x16 lacc = {};   // per-slot P-sum accumulator

  // staging offsets: 8 chunks of 64 granules; 2 K-gloads + 2 V-gloads per thread
  int koff[2], voff[2];
#pragma unroll
  for (int i = 0; i < 2; ++i) {
    const int chunk = i * 4 + wq;
    const int gid = chunk * 64 + lane;
    const int row = gid >> 3, gk = gid & 7;
    const int key = (row ^ (row >> 3)) & 7;
    koff[i] = row * 64 + ((gk ^ key) << 3);
    voff[i] = row * 2048 + ((gk ^ key) << 3);
  }

  // prologue: stage tile 0
#pragma unroll
  for (int i = 0; i < 2; ++i) {
    const int chunk = i * 4 + wq;
    gload16(Kp + koff[i], &Ks[0][chunk * 512]);
    gload16(VtP + voff[i], &Vt[0][chunk * 512]);
  }
  __syncthreads();

  int cur = 0;
  for (int it = 0; it < 16; ++it) {
    const int kv0 = it * 64;
    if (it < 15) {  // async prefetch next tile (T14)
#pragma unroll
      for (int i = 0; i < 2; ++i) {
        const int chunk = i * 4 + wq;
        gload16(Kp + (kv0 + 64) * 64 + koff[i], &Ks[cur ^ 1][chunk * 512]);
        gload16(VtP + (kv0 + 64) + voff[i], &Vt[cur ^ 1][chunk * 512]);
      }
    }
    const bf16* ks = &Ks[cur][0];
    const bf16* vt = &Vt[cur][0];

    // S^T - 12 = K * Q^T + (-12)
    f32x16 sv[2];
#pragma unroll
    for (int jt = 0; jt < 2; ++jt)
#pragma unroll
      for (int r = 0; r < 16; ++r) sv[jt][r] = -SMAX;
    __builtin_amdgcn_s_setprio(1);
#pragma unroll
    for (int jt = 0; jt < 2; ++jt) {
      const int j = jt * 32 + l31;
      const int key = (j ^ (j >> 3)) & 7;
#pragma unroll
      for (int kc = 0; kc < 4; ++kc) {
        bf16x8 kf = *(const bf16x8*)&ks[j * 64 + (((2 * kc + hi) ^ key) << 3)];
        sv[jt] = __builtin_amdgcn_mfma_f32_32x32x16_bf16(kf, qf[kc], sv[jt], 0, 0, 0);
      }
    }
    __builtin_amdgcn_s_setprio(0);

    // P = exp2(S' - 12)
#pragma unroll
    for (int jt = 0; jt < 2; ++jt)
#pragma unroll
      for (int r = 0; r < 16; ++r) sv[jt][r] = fexp2(sv[jt][r]);

#pragma unroll
    for (int r = 0; r < 16; ++r) lacc[r] += sv[0][r] + sv[1][r];

    // P (C-layout, q=lane) -> bf16 B-frags: pack + half-wave exchange (proven mapping)
    u32 w[2][8];
#pragma unroll
    for (int jt = 0; jt < 2; ++jt)
#pragma unroll
      for (int i = 0; i < 8; ++i) w[jt][i] = pack2(sv[jt][2 * i], sv[jt][2 * i + 1]);
    bf16x8 pafr[4];
#pragma unroll
    for (int kc = 0; kc < 4; ++kc) {
      const int c = kc & 1, jt = kc >> 1;
      const u32 z1 = hi ? w[jt][4 * c + 0] : w[jt][4 * c + 2];
      const u32 z2 = hi ? w[jt][4 * c + 1] : w[jt][4 * c + 3];
      const u32 r1 = __shfl_xor(z1, 32);
      const u32 r2 = __shfl_xor(z2, 32);
      u32x4 pv;
      pv[0] = hi ? r1 : w[jt][4 * c + 0];
      pv[1] = hi ? r2 : w[jt][4 * c + 1];
      pv[2] = hi ? w[jt][4 * c + 2] : r1;
      pv[3] = hi ? w[jt][4 * c + 3] : r2;
      pafr[kc] = __builtin_bit_cast(bf16x8, pv);
    }

    // O^T += V^T * P : j-dim 64 (4 kc)
    __builtin_amdgcn_s_setprio(1);
#pragma unroll
    for (int dt = 0; dt < 2; ++dt) {
      const int d = dt * 32 + l31;
      const int key = (d ^ (d >> 3)) & 7;
#pragma unroll
      for (int kc = 0; kc < 4; ++kc) {
        bf16x8 vf = *(const bf16x8*)&vt[d * 64 + (((2 * kc + hi) ^ key) << 3)];
        o[dt] = __builtin_amdgcn_mfma_f32_32x32x16_bf16(vf, pafr[kc], o[dt], 0, 0, 0);
      }
    }
    __builtin_amdgcn_s_setprio(0);

    __syncthreads();
    cur ^= 1;
  }

  // partial row-sum
  float sm[16];
#pragma unroll
  for (int r = 0; r < 16; ++r) sm[r] = lacc[r];
#pragma unroll
  for (int s2 = 8; s2 > 0; s2 >>= 1)
#pragma unroll
    for (int r = 0; r < s2; ++r) sm[r] += sm[r + s2];
  const float lpart = sm[0] + __shfl_xor(sm[0], 32);

  // partial O store in [bh][d][n]: lane l31 = consecutive n -> coalesced (two 64B runs)
  bf16* P = half ? P1 : P0;
#pragma unroll
  for (int dt = 0; dt < 2; ++dt)
#pragma unroll
    for (int rr = 0; rr < 4; ++rr)
#pragma unroll
      for (int e = 0; e < 4; ++e) {
        const int r = rr * 4 + e;
        const int d = e + 8 * rr + 4 * hi + 32 * dt;
        P[((long)bh * 64 + d) * 2048 + qrow] = (bf16)o[dt][r];
      }
  if (hi == 0) Lp[half * 65536 + bh * 2048 + qrow] = lpart;
}

// ---------------- merge: tile-based, coalesced; y=(O0+O1)/l with xsa projection --------
// grid: 32 bh * 32 n-tiles of 64; loads P0/P1/Vt [64d][64n] tiles coalesced into LDS
// (stride 72 vs bank conflicts), computes per-n dot over d with 4-lane reduce.
__global__ __launch_bounds__(256) void attn_merge_kernel(
    const bf16* __restrict__ P0, const bf16* __restrict__ P1, const bf16* __restrict__ VtG,
    const float* __restrict__ Lp, const float* __restrict__ vninv, bf16* __restrict__ Yb) {
  __shared__ bf16 Os[64 * 72];
  __shared__ bf16 Vs[64 * 72];
  const int tid = threadIdx.x;
  const int bh = blockIdx.x >> 5, nt = blockIdx.x & 31;
  const int n0 = nt * 64;
  const int b = bh >> 4, h = bh & 15;

  {  // load phase: thread -> d = tid>>2, 16-n segment = tid&3
    const int d = tid >> 2, seg = tid & 3;
    const long src = ((long)bh * 64 + d) * 2048 + n0 + seg * 16;
    const bf16x8 a0 = *(const bf16x8*)(P0 + src);
    const bf16x8 a1 = *(const bf16x8*)(P0 + src + 8);
    const bf16x8 c0 = *(const bf16x8*)(P1 + src);
    const bf16x8 c1 = *(const bf16x8*)(P1 + src + 8);
    bf16x8 s0, s1;
#pragma unroll
    for (int e = 0; e < 8; ++e) {
      s0[e] = (bf16)((float)a0[e] + (float)c0[e]);
      s1[e] = (bf16)((float)a1[e] + (float)c1[e]);
    }
    *(bf16x8*)&Os[d * 72 + seg * 16] = s0;
    *(bf16x8*)&Os[d * 72 + seg * 16 + 8] = s1;
    *(bf16x8*)&Vs[d * 72 + seg * 16] = *(const bf16x8*)(VtG + src);
    *(bf16x8*)&Vs[d * 72 + seg * 16 + 8] = *(const bf16x8*)(VtG + src + 8);
  }
  __syncthreads();

  // compute phase: thread -> n = tid>>2 (0..63), d-group = tid&3 (16 d each)
  const int n = tid >> 2, dg = tid & 3;
  const int qg = bh * 2048 + n0 + n;
  const float linv = 1.f / (Lp[qg] + Lp[65536 + qg]);
  float os[16], vs[16];
  float pd = 0.f;
#pragma unroll
  for (int i = 0; i < 16; ++i) {
    const int dd = dg * 16 + i;
    os[i] = (float)Os[dd * 72 + n];
    vs[i] = (float)Vs[dd * 72 + n];
    pd += os[i] * vs[i];
  }
  pd += __shfl_xor(pd, 1);
  pd += __shfl_xor(pd, 2);
  const float vni = vninv[qg];
  const float coef = pd * linv * vni * vni;
  bf16x8 y0, y1;
#pragma unroll
  for (int i = 0; i < 8; ++i) {
    y0[i] = (bf16)(linv * os[i] - coef * vs[i]);
    y1[i] = (bf16)(linv * os[i + 8] - coef * vs[i + 8]);
  }
  bf16* yp = Yb + ((long)b * 2048 + n0 + n) * 1024 + h * 64 + dg * 16;
  *(bf16x8*)yp = y0;
  *(bf16x8*)(yp + 8) = y1;
}

// ---------------- launch ----------------
extern "C" void kernel_launch(void* const* d_in, const int* in_sizes, int n_in,
                              void* d_out, int out_size, void* d_ws, size_t ws_size,
                              hipStream_t stream) {
  (void)in_sizes; (void)n_in; (void)out_size; (void)ws_size;
  const float* x = (const float*)d_in[0];
  const float* w_qkv = (const float*)d_in[1];
  const float* w_proj = (const float*)d_in[2];
  float* out = (float*)d_out;
  char* ws = (char*)d_ws;

  bf16* xb     = (bf16*)(ws);              //  8,388,608  x bf16 (dead after gemm1 -> P0)
  bf16* wqkvb  = (bf16*)(ws + 8388608);    //  6,291,456  (dead after gemm1 -> Lp)
  bf16* wprojb = (bf16*)(ws + 14680064);   //  2,097,152
  bf16* Qb     = (bf16*)(ws + 16777216);   //  8,388,608  rms-normed * 0.125*log2e
  bf16* Kb     = (bf16*)(ws + 25165824);   //  8,388,608  rms-normed
  bf16* VtG    = (bf16*)(ws + 33554432);   //  8,388,608  (B,H,D,N) V transposed
  float* vninv = (float*)(ws + 41943040);  //    524,288  1/max(||v||,1e-12)
  bf16* Yb     = (bf16*)(ws + 42467328);   //  8,388,608  final Y (B,N,C)

  bf16* P0  = xb;                          // split-0 partial O, [bh][d][n]
  bf16* P1  = (bf16*)out;                  // split-1 partial O (d_out as scratch;
                                           // gemm0 fully overwrites out afterwards)
  float* Lp = (float*)(ws + 8388608);      // [2][65536] f32 partial row-sums

  cvt3_kernel<<<4096, 256, 0, stream>>>(x, w_qkv, w_proj, xb, wqkvb, wprojb);

  gemm_bt<1, 3><<<dim3(24, 32), 256, 0, stream>>>(xb, wqkvb, nullptr, 3072,
                                                  Qb, Kb, VtG, vninv);
  attn_split_kernel<<<1024, 256, 0, stream>>>(Qb, Kb, VtG, P0, P1, Lp);
  attn_merge_kernel<<<1024, 256, 0, stream>>>(P0, P1, VtG, Lp, vninv, Yb);
  gemm_bt<0, 2><<<dim3(8, 32), 256, 0, stream>>>(Yb, wprojb, out, 1024,
                                                 nullptr, nullptr, nullptr, nullptr);
}

// Round 19
// 128.728 us; speedup vs baseline: 1.2575x; 1.2417x over previous
//
#include <hip/hip_runtime.h>
#include <hip/hip_bf16.h>
#include <cstdint>

// Problem constants: B=2, N=2048, C=1024, H=16, D=64
// Q is stored pre-scaled by D^-0.5 * log2(e) so softmax runs in exp2 domain.
// V is materialized TRANSPOSED in global memory (VtG[bh][d][n]) by the QKV GEMM.
// STATIC-MAX softmax: rms_norm bounds |S'| <= 8*log2e = 11.54 < 12, so P = exp2(S' - 12).
// Attention is KV-SPLIT into 2 half-KV passes + tile-based merge.
// LESSON (R13/R17/R18): __launch_bounds__ 2nd arg >2 caps VGPR below the ~90 this body
// needs -> per-iteration scratch spill (the 119MB "write amplification" was spill I/O).
// (256,2) is the proven no-spill bound; runtime occupancy (4-5 blocks/CU) comes from the
// ACTUAL VGPR/LDS use, which launch_bounds does not limit.
#define RMS_EPS 1.1920928955078125e-07f
#define SMAX 12.0f

typedef __bf16 bf16;
typedef __attribute__((ext_vector_type(8))) __bf16 bf16x8;
typedef __attribute__((ext_vector_type(4))) __bf16 bf16x4;
typedef __attribute__((ext_vector_type(4))) float f32x4;
typedef __attribute__((ext_vector_type(16))) float f32x16;
typedef unsigned int u32;
typedef __attribute__((ext_vector_type(4))) u32 u32x4;

__device__ __forceinline__ void gload16(const bf16* g, bf16* l) {
  __builtin_amdgcn_global_load_lds(
      (__attribute__((address_space(1))) void*)(g),
      (__attribute__((address_space(3))) void*)(l), 16, 0, 0);
}

__device__ __forceinline__ float fexp2(float x) {
#if __has_builtin(__builtin_amdgcn_exp2f)
  return __builtin_amdgcn_exp2f(x);
#else
  return exp2f(x);
#endif
}

__device__ __forceinline__ u32 pack2(float a, float b) {
  unsigned short xa = __builtin_bit_cast(unsigned short, (bf16)a);
  unsigned short xb = __builtin_bit_cast(unsigned short, (bf16)b);
  return (u32)xa | ((u32)xb << 16);
}

// ---------------- fused f32 -> bf16 convert for all three inputs ----------------
__global__ __launch_bounds__(256) void cvt3_kernel(
    const float* __restrict__ x, const float* __restrict__ wq, const float* __restrict__ wp,
    bf16* __restrict__ xo, bf16* __restrict__ wqo, bf16* __restrict__ wpo) {
  int i = blockIdx.x * 256 + threadIdx.x;
  const float* s; bf16* d; int off;
  if (i < 524288) { s = x; d = xo; off = i; }
  else if (i < 917504) { s = wq; d = wqo; off = i - 524288; }
  else { s = wp; d = wpo; off = i - 917504; }
  const float4* s4 = (const float4*)s;
  float4 a = s4[off * 2], b = s4[off * 2 + 1];
  bf16x8 o;
  o[0] = (bf16)a.x; o[1] = (bf16)a.y; o[2] = (bf16)a.z; o[3] = (bf16)a.w;
  o[4] = (bf16)b.x; o[5] = (bf16)b.y; o[6] = (bf16)b.z; o[7] = (bf16)b.w;
  *(bf16x8*)(d + off * 8) = o;
}

// ---------------- GEMM C = A * B^T (R16, proven) ----------------
template <int MODE, int MINW>
__global__ __launch_bounds__(256, MINW) void gemm_bt(
    const bf16* __restrict__ A, const bf16* __restrict__ B,
    float* __restrict__ Cout, int Ncols,
    bf16* __restrict__ Qb, bf16* __restrict__ Kb, bf16* __restrict__ VtG,
    float* __restrict__ vninv) {
  union ShG {
    struct { bf16 As[128 * 64]; bf16 Bs[128 * 64]; } s;
    bf16 T[128 * 136];
  };
  __shared__ ShG shg;
  bf16* As = shg.s.As;
  bf16* Bs = shg.s.Bs;

  const int tid = threadIdx.x;
  const int wave = tid >> 6, lane = tid & 63;
  const int l15 = lane & 15, g = lane >> 4;
  const int nwg = gridDim.x * gridDim.y;
  const int wg0 = blockIdx.y * gridDim.x + blockIdx.x;
  const int wg = (wg0 & 7) * (nwg >> 3) + (wg0 >> 3);
  const int m0 = (wg / gridDim.x) * 128, n0 = (wg % gridDim.x) * 128;
  const int wr = wave >> 1, wc = wave & 1;

  f32x4 acc[4][4] = {};

  for (int k0 = 0; k0 < 1024; k0 += 64) {
    __syncthreads();
#pragma unroll
    for (int i = 0; i < 4; ++i) {
      const int gid = (i * 4 + wave) * 64 + lane;
      const int row = gid >> 3, gk = gid & 7;
      const int srcoff = k0 + ((gk ^ (row & 7)) << 3);
      gload16(A + (m0 + row) * 1024 + srcoff, As + (i * 4 + wave) * 512);
      gload16(B + (n0 + row) * 1024 + srcoff, Bs + (i * 4 + wave) * 512);
    }
    __syncthreads();
#pragma unroll
    for (int kc = 0; kc < 2; ++kc) {
      bf16x8 af[4], bfb[4];
#pragma unroll
      for (int mi = 0; mi < 4; ++mi) {
        const int row = wr * 64 + mi * 16 + l15;
        af[mi] = *(const bf16x8*)&As[row * 64 + (((kc * 4 + g) ^ (l15 & 7)) << 3)];
      }
#pragma unroll
      for (int ni = 0; ni < 4; ++ni) {
        const int row = wc * 64 + ni * 16 + l15;
        bfb[ni] = *(const bf16x8*)&Bs[row * 64 + (((kc * 4 + g) ^ (l15 & 7)) << 3)];
      }
#pragma unroll
      for (int mi = 0; mi < 4; ++mi)
#pragma unroll
        for (int ni = 0; ni < 4; ++ni)
          acc[mi][ni] = __builtin_amdgcn_mfma_f32_16x16x32_bf16(af[mi], bfb[ni], acc[mi][ni], 0, 0, 0);
    }
  }

  if (MODE == 0) {
#pragma unroll
    for (int mi = 0; mi < 4; ++mi) {
      const int mrow = m0 + wr * 64 + mi * 16 + g * 4;
#pragma unroll
      for (int r = 0; r < 4; ++r) {
        float* cp = Cout + (long)(mrow + r) * Ncols + n0 + wc * 64 + l15;
#pragma unroll
        for (int ni = 0; ni < 4; ++ni) cp[ni * 16] = acc[mi][ni][r];
      }
    }
  } else {
    const int blk_which = n0 >> 10;
    const int ncol = n0 + wc * 64;
    const int h = (ncol >> 6) & 15;

    if (blk_which == 2) {
#pragma unroll
      for (int mi = 0; mi < 4; ++mi) {
#pragma unroll
        for (int r = 0; r < 4; ++r) {
          float ss = 0.f;
#pragma unroll
          for (int ni = 0; ni < 4; ++ni) ss += acc[mi][ni][r] * acc[mi][ni][r];
          ss += __shfl_xor(ss, 1); ss += __shfl_xor(ss, 2);
          ss += __shfl_xor(ss, 4); ss += __shfl_xor(ss, 8);
          if (l15 == 0) {
            const int m = m0 + wr * 64 + mi * 16 + g * 4 + r;
            const int b = m >> 11, nseq = m & 2047;
            vninv[(b * 16 + h) * 2048 + nseq] = 1.0f / fmaxf(sqrtf(ss), 1e-12f);
          }
        }
      }
      __syncthreads();
#pragma unroll
      for (int mi = 0; mi < 4; ++mi)
#pragma unroll
        for (int ni = 0; ni < 4; ++ni) {
          bf16x4 v4;
#pragma unroll
          for (int r = 0; r < 4; ++r) v4[r] = (bf16)acc[mi][ni][r];
          *(bf16x4*)&shg.T[(wc * 64 + ni * 16 + l15) * 136 + wr * 64 + mi * 16 + g * 4] = v4;
        }
      __syncthreads();
      const int c = tid >> 1, half = tid & 1;
      const int gcol = n0 + c;
      const int hh = (gcol >> 6) & 15, d = gcol & 63;
      const int mb = m0 >> 11, nseq0 = m0 & 2047;
      bf16* dst = VtG + ((long)(mb * 16 + hh) * 64 + d) * 2048 + nseq0 + half * 64;
      const bf16* src = &shg.T[c * 136 + half * 64];
#pragma unroll
      for (int i = 0; i < 8; ++i)
        *(bf16x8*)(dst + i * 8) = *(const bf16x8*)(src + i * 8);
    } else {
      float scv[4][4];
#pragma unroll
      for (int mi = 0; mi < 4; ++mi) {
#pragma unroll
        for (int r = 0; r < 4; ++r) {
          float ss = 0.f;
#pragma unroll
          for (int ni = 0; ni < 4; ++ni) ss += acc[mi][ni][r] * acc[mi][ni][r];
          ss += __shfl_xor(ss, 1); ss += __shfl_xor(ss, 2);
          ss += __shfl_xor(ss, 4); ss += __shfl_xor(ss, 8);
          const float sc = rsqrtf(ss * (1.0f / 64) + RMS_EPS);
          scv[mi][r] = (blk_which == 0) ? sc * (0.125f * 1.44269504088896340736f) : sc;
        }
      }
      __syncthreads();
#pragma unroll
      for (int mi = 0; mi < 4; ++mi)
#pragma unroll
        for (int r = 0; r < 4; ++r) {
          const float sc = scv[mi][r];
#pragma unroll
          for (int ni = 0; ni < 4; ++ni)
            shg.T[(wr * 64 + mi * 16 + g * 4 + r) * 136 + wc * 64 + ni * 16 + l15] =
                (bf16)(acc[mi][ni][r] * sc);
        }
      __syncthreads();
      bf16* QK = (blk_which == 0) ? Qb : Kb;
      const int c8 = tid & 7, chh = (tid >> 3) & 1, r0 = tid >> 4;
      const int hh = ((n0 + chh * 64) >> 6) & 15;
#pragma unroll
      for (int p = 0; p < 8; ++p) {
        const int rr = r0 + p * 16;
        const int m = m0 + rr;
        const int bq = m >> 11, nseq = m & 2047;
        *(bf16x8*)(QK + ((long)(bq * 16 + hh) * 2048 + nseq) * 64 + c8 * 8) =
            *(const bf16x8*)&shg.T[rr * 136 + chh * 64 + c8 * 8];
      }
    }
  }
}

// ---------------- attention KV-split pass: 4 waves x 32x32 MFMA, KVBLK=64 ----------------
// grid: 32 bh * 16 qb * 2 halves = 1024 blocks; 256 threads; 32KB LDS.
// __launch_bounds__(256,2): no VGPR cap below natural need (no spill); LDS+VGPR let the
// hardware co-schedule 4-5 blocks/CU at runtime.
__global__ __launch_bounds__(256, 2) void attn_split_kernel(
    const bf16* __restrict__ Qb, const bf16* __restrict__ Kb, const bf16* __restrict__ VtG,
    bf16* __restrict__ P0, bf16* __restrict__ P1, float* __restrict__ Lp) {
  __shared__ bf16 Ks[2][64 * 64];  // [j][d], swizzle key (j^(j>>3))&7
  __shared__ bf16 Vt[2][64 * 64];  // [d][j], swizzle key (d^(d>>3))&7

  const int tid = threadIdx.x;
  const int wq = tid >> 6;
  const int lane = tid & 63;
  const int l31 = lane & 31, hi = lane >> 5;
  // XCD swizzle (1024 % 8 == 0 -> bijective)
  const int wg = (blockIdx.x & 7) * (gridDim.x >> 3) + (blockIdx.x >> 3);
  const int bh = wg >> 5, qb = (wg >> 1) & 15, half = wg & 1;
  const long off = (long)bh * (2048 * 64);
  const bf16* Qp = Qb + off;
  const bf16* Kp = Kb + off + (long)(half * 1024) * 64;
  const bf16* VtP = VtG + (long)bh * 64 * 2048 + half * 1024;
  const int qrow = qb * 128 + wq * 32 + l31;

  // Q B-frags: row q=l31, k = kc*16 + hi*8 + i
  bf16x8 qf[4];
#pragma unroll
  for (int kc = 0; kc < 4; ++kc)
    qf[kc] = *(const bf16x8*)&Qp[qrow * 64 + kc * 16 + hi * 8];

  f32x16 o[2] = {};   // O^T[d][q]: q=l31, d = (r&3)+8*(r>>2)+4*hi+32*dt
  f32x16 lacc = {};   // per-slot P-sum accumulator

  // staging offsets: 8 chunks of 64 granules; 2 K-gloads + 2 V-gloads per thread
  int koff[2], voff[2];
#pragma unroll
  for (int i = 0; i < 2; ++i) {
    const int chunk = i * 4 + wq;
    const int gid = chunk * 64 + lane;
    const int row = gid >> 3, gk = gid & 7;
    const int key = (row ^ (row >> 3)) & 7;
    koff[i] = row * 64 + ((gk ^ key) << 3);
    voff[i] = row * 2048 + ((gk ^ key) << 3);
  }

  // prologue: stage tile 0
#pragma unroll
  for (int i = 0; i < 2; ++i) {
    const int chunk = i * 4 + wq;
    gload16(Kp + koff[i], &Ks[0][chunk * 512]);
    gload16(VtP + voff[i], &Vt[0][chunk * 512]);
  }
  __syncthreads();

  int cur = 0;
  for (int it = 0; it < 16; ++it) {
    const int kv0 = it * 64;
    if (it < 15) {  // async prefetch next tile (T14)
#pragma unroll
      for (int i = 0; i < 2; ++i) {
        const int chunk = i * 4 + wq;
        gload16(Kp + (kv0 + 64) * 64 + koff[i], &Ks[cur ^ 1][chunk * 512]);
        gload16(VtP + (kv0 + 64) + voff[i], &Vt[cur ^ 1][chunk * 512]);
      }
    }
    const bf16* ks = &Ks[cur][0];
    const bf16* vt = &Vt[cur][0];

    // S^T - 12 = K * Q^T + (-12)
    f32x16 sv[2];
#pragma unroll
    for (int jt = 0; jt < 2; ++jt)
#pragma unroll
      for (int r = 0; r < 16; ++r) sv[jt][r] = -SMAX;
    __builtin_amdgcn_s_setprio(1);
#pragma unroll
    for (int jt = 0; jt < 2; ++jt) {
      const int j = jt * 32 + l31;
      const int key = (j ^ (j >> 3)) & 7;
#pragma unroll
      for (int kc = 0; kc < 4; ++kc) {
        bf16x8 kf = *(const bf16x8*)&ks[j * 64 + (((2 * kc + hi) ^ key) << 3)];
        sv[jt] = __builtin_amdgcn_mfma_f32_32x32x16_bf16(kf, qf[kc], sv[jt], 0, 0, 0);
      }
    }
    __builtin_amdgcn_s_setprio(0);

    // P = exp2(S' - 12)
#pragma unroll
    for (int jt = 0; jt < 2; ++jt)
#pragma unroll
      for (int r = 0; r < 16; ++r) sv[jt][r] = fexp2(sv[jt][r]);

#pragma unroll
    for (int r = 0; r < 16; ++r) lacc[r] += sv[0][r] + sv[1][r];

    // P (C-layout, q=lane) -> bf16 B-frags: pack + half-wave exchange (proven mapping)
    u32 w[2][8];
#pragma unroll
    for (int jt = 0; jt < 2; ++jt)
#pragma unroll
      for (int i = 0; i < 8; ++i) w[jt][i] = pack2(sv[jt][2 * i], sv[jt][2 * i + 1]);
    bf16x8 pafr[4];
#pragma unroll
    for (int kc = 0; kc < 4; ++kc) {
      const int c = kc & 1, jt = kc >> 1;
      const u32 z1 = hi ? w[jt][4 * c + 0] : w[jt][4 * c + 2];
      const u32 z2 = hi ? w[jt][4 * c + 1] : w[jt][4 * c + 3];
      const u32 r1 = __shfl_xor(z1, 32);
      const u32 r2 = __shfl_xor(z2, 32);
      u32x4 pv;
      pv[0] = hi ? r1 : w[jt][4 * c + 0];
      pv[1] = hi ? r2 : w[jt][4 * c + 1];
      pv[2] = hi ? w[jt][4 * c + 2] : r1;
      pv[3] = hi ? w[jt][4 * c + 3] : r2;
      pafr[kc] = __builtin_bit_cast(bf16x8, pv);
    }

    // O^T += V^T * P : j-dim 64 (4 kc)
    __builtin_amdgcn_s_setprio(1);
#pragma unroll
    for (int dt = 0; dt < 2; ++dt) {
      const int d = dt * 32 + l31;
      const int key = (d ^ (d >> 3)) & 7;
#pragma unroll
      for (int kc = 0; kc < 4; ++kc) {
        bf16x8 vf = *(const bf16x8*)&vt[d * 64 + (((2 * kc + hi) ^ key) << 3)];
        o[dt] = __builtin_amdgcn_mfma_f32_32x32x16_bf16(vf, pafr[kc], o[dt], 0, 0, 0);
      }
    }
    __builtin_amdgcn_s_setprio(0);

    __syncthreads();
    cur ^= 1;
  }

  // partial row-sum
  float sm[16];
#pragma unroll
  for (int r = 0; r < 16; ++r) sm[r] = lacc[r];
#pragma unroll
  for (int s2 = 8; s2 > 0; s2 >>= 1)
#pragma unroll
    for (int r = 0; r < s2; ++r) sm[r] += sm[r + s2];
  const float lpart = sm[0] + __shfl_xor(sm[0], 32);

  // partial O store in [bh][d][n]: lane l31 = consecutive n -> coalesced (two 64B runs)
  bf16* P = half ? P1 : P0;
#pragma unroll
  for (int dt = 0; dt < 2; ++dt)
#pragma unroll
    for (int rr = 0; rr < 4; ++rr)
#pragma unroll
      for (int e = 0; e < 4; ++e) {
        const int r = rr * 4 + e;
        const int d = e + 8 * rr + 4 * hi + 32 * dt;
        P[((long)bh * 64 + d) * 2048 + qrow] = (bf16)o[dt][r];
      }
  if (hi == 0) Lp[half * 65536 + bh * 2048 + qrow] = lpart;
}

// ---------------- merge: tile-based, coalesced; y=(O0+O1)/l with xsa projection --------
__global__ __launch_bounds__(256) void attn_merge_kernel(
    const bf16* __restrict__ P0, const bf16* __restrict__ P1, const bf16* __restrict__ VtG,
    const float* __restrict__ Lp, const float* __restrict__ vninv, bf16* __restrict__ Yb) {
  __shared__ bf16 Os[64 * 72];
  __shared__ bf16 Vs[64 * 72];
  const int tid = threadIdx.x;
  const int bh = blockIdx.x >> 5, nt = blockIdx.x & 31;
  const int n0 = nt * 64;
  const int b = bh >> 4, h = bh & 15;

  {  // load phase: thread -> d = tid>>2, 16-n segment = tid&3
    const int d = tid >> 2, seg = tid & 3;
    const long src = ((long)bh * 64 + d) * 2048 + n0 + seg * 16;
    const bf16x8 a0 = *(const bf16x8*)(P0 + src);
    const bf16x8 a1 = *(const bf16x8*)(P0 + src + 8);
    const bf16x8 c0 = *(const bf16x8*)(P1 + src);
    const bf16x8 c1 = *(const bf16x8*)(P1 + src + 8);
    bf16x8 s0, s1;
#pragma unroll
    for (int e = 0; e < 8; ++e) {
      s0[e] = (bf16)((float)a0[e] + (float)c0[e]);
      s1[e] = (bf16)((float)a1[e] + (float)c1[e]);
    }
    *(bf16x8*)&Os[d * 72 + seg * 16] = s0;
    *(bf16x8*)&Os[d * 72 + seg * 16 + 8] = s1;
    *(bf16x8*)&Vs[d * 72 + seg * 16] = *(const bf16x8*)(VtG + src);
    *(bf16x8*)&Vs[d * 72 + seg * 16 + 8] = *(const bf16x8*)(VtG + src + 8);
  }
  __syncthreads();

  // compute phase: thread -> n = tid>>2 (0..63), d-group = tid&3 (16 d each)
  const int n = tid >> 2, dg = tid & 3;
  const int qg = bh * 2048 + n0 + n;
  const float linv = 1.f / (Lp[qg] + Lp[65536 + qg]);
  float os[16], vs[16];
  float pd = 0.f;
#pragma unroll
  for (int i = 0; i < 16; ++i) {
    const int dd = dg * 16 + i;
    os[i] = (float)Os[dd * 72 + n];
    vs[i] = (float)Vs[dd * 72 + n];
    pd += os[i] * vs[i];
  }
  pd += __shfl_xor(pd, 1);
  pd += __shfl_xor(pd, 2);
  const float vni = vninv[qg];
  const float coef = pd * linv * vni * vni;
  bf16x8 y0, y1;
#pragma unroll
  for (int i = 0; i < 8; ++i) {
    y0[i] = (bf16)(linv * os[i] - coef * vs[i]);
    y1[i] = (bf16)(linv * os[i + 8] - coef * vs[i + 8]);
  }
  bf16* yp = Yb + ((long)b * 2048 + n0 + n) * 1024 + h * 64 + dg * 16;
  *(bf16x8*)yp = y0;
  *(bf16x8*)(yp + 8) = y1;
}

// ---------------- launch ----------------
extern "C" void kernel_launch(void* const* d_in, const int* in_sizes, int n_in,
                              void* d_out, int out_size, void* d_ws, size_t ws_size,
                              hipStream_t stream) {
  (void)in_sizes; (void)n_in; (void)out_size; (void)ws_size;
  const float* x = (const float*)d_in[0];
  const float* w_qkv = (const float*)d_in[1];
  const float* w_proj = (const float*)d_in[2];
  float* out = (float*)d_out;
  char* ws = (char*)d_ws;

  bf16* xb     = (bf16*)(ws);              //  8,388,608  x bf16 (dead after gemm1 -> P0)
  bf16* wqkvb  = (bf16*)(ws + 8388608);    //  6,291,456  (dead after gemm1 -> Lp)
  bf16* wprojb = (bf16*)(ws + 14680064);   //  2,097,152
  bf16* Qb     = (bf16*)(ws + 16777216);   //  8,388,608  rms-normed * 0.125*log2e
  bf16* Kb     = (bf16*)(ws + 25165824);   //  8,388,608  rms-normed
  bf16* VtG    = (bf16*)(ws + 33554432);   //  8,388,608  (B,H,D,N) V transposed
  float* vninv = (float*)(ws + 41943040);  //    524,288  1/max(||v||,1e-12)
  bf16* Yb     = (bf16*)(ws + 42467328);   //  8,388,608  final Y (B,N,C)

  bf16* P0  = xb;                          // split-0 partial O, [bh][d][n]
  bf16* P1  = (bf16*)out;                  // split-1 partial O (d_out as scratch;
                                           // gemm0 fully overwrites out afterwards)
  float* Lp = (float*)(ws + 8388608);      // [2][65536] f32 partial row-sums

  cvt3_kernel<<<4096, 256, 0, stream>>>(x, w_qkv, w_proj, xb, wqkvb, wprojb);

  gemm_bt<1, 3><<<dim3(24, 32), 256, 0, stream>>>(xb, wqkvb, nullptr, 3072,
                                                  Qb, Kb, VtG, vninv);
  attn_split_kernel<<<1024, 256, 0, stream>>>(Qb, Kb, VtG, P0, P1, Lp);
  attn_merge_kernel<<<1024, 256, 0, stream>>>(P0, P1, VtG, Lp, vninv, Yb);
  gemm_bt<0, 2><<<dim3(8, 32), 256, 0, stream>>>(Yb, wprojb, out, 1024,
                                                 nullptr, nullptr, nullptr, nullptr);
}

// Round 20
// 123.053 us; speedup vs baseline: 1.3155x; 1.0461x over previous
//
#include <hip/hip_runtime.h>
#include <hip/hip_bf16.h>
#include <cstdint>

// Problem constants: B=2, N=2048, C=1024, H=16, D=64
// Q is stored pre-scaled by D^-0.5 * log2(e) so softmax runs in exp2 domain.
// V is materialized TRANSPOSED in global memory (VtG[bh][d][n]) by the QKV GEMM.
// STATIC-MAX softmax: rms_norm bounds |S'| <= 8*log2e = 11.54 < 12, so P = exp2(S' - 12)
// needs no online max tracking; -12 is folded into the QK^T MFMA C-initializer.
// R20: monolithic attn (proven best) with s_setprio REMOVED — m190 evidence says raised
// priority around MFMA clusters starves co-resident waves' VALU in lockstep loops,
// blocking exactly the cross-wave overlap we need.
#define RMS_EPS 1.1920928955078125e-07f
#define SMAX 12.0f

typedef __bf16 bf16;
typedef __attribute__((ext_vector_type(8))) __bf16 bf16x8;
typedef __attribute__((ext_vector_type(4))) __bf16 bf16x4;
typedef __attribute__((ext_vector_type(4))) float f32x4;
typedef __attribute__((ext_vector_type(16))) float f32x16;
typedef unsigned int u32;
typedef __attribute__((ext_vector_type(4))) u32 u32x4;

__device__ __forceinline__ void gload16(const bf16* g, bf16* l) {
  __builtin_amdgcn_global_load_lds(
      (__attribute__((address_space(1))) void*)(g),
      (__attribute__((address_space(3))) void*)(l), 16, 0, 0);
}

__device__ __forceinline__ float fexp2(float x) {
#if __has_builtin(__builtin_amdgcn_exp2f)
  return __builtin_amdgcn_exp2f(x);
#else
  return exp2f(x);
#endif
}

__device__ __forceinline__ u32 pack2(float a, float b) {
  unsigned short xa = __builtin_bit_cast(unsigned short, (bf16)a);
  unsigned short xb = __builtin_bit_cast(unsigned short, (bf16)b);
  return (u32)xa | ((u32)xb << 16);
}

// ---------------- fused f32 -> bf16 convert for all three inputs ----------------
__global__ __launch_bounds__(256) void cvt3_kernel(
    const float* __restrict__ x, const float* __restrict__ wq, const float* __restrict__ wp,
    bf16* __restrict__ xo, bf16* __restrict__ wqo, bf16* __restrict__ wpo) {
  int i = blockIdx.x * 256 + threadIdx.x;
  const float* s; bf16* d; int off;
  if (i < 524288) { s = x; d = xo; off = i; }
  else if (i < 917504) { s = wq; d = wqo; off = i - 524288; }
  else { s = wp; d = wpo; off = i - 917504; }
  const float4* s4 = (const float4*)s;
  float4 a = s4[off * 2], b = s4[off * 2 + 1];
  bf16x8 o;
  o[0] = (bf16)a.x; o[1] = (bf16)a.y; o[2] = (bf16)a.z; o[3] = (bf16)a.w;
  o[4] = (bf16)b.x; o[5] = (bf16)b.y; o[6] = (bf16)b.z; o[7] = (bf16)b.w;
  *(bf16x8*)(d + off * 8) = o;
}

// ---------------- GEMM C = A * B^T (R16, proven) ----------------
template <int MODE, int MINW>
__global__ __launch_bounds__(256, MINW) void gemm_bt(
    const bf16* __restrict__ A, const bf16* __restrict__ B,
    float* __restrict__ Cout, int Ncols,
    bf16* __restrict__ Qb, bf16* __restrict__ Kb, bf16* __restrict__ VtG,
    float* __restrict__ vninv) {
  union ShG {
    struct { bf16 As[128 * 64]; bf16 Bs[128 * 64]; } s;
    bf16 T[128 * 136];
  };
  __shared__ ShG shg;
  bf16* As = shg.s.As;
  bf16* Bs = shg.s.Bs;

  const int tid = threadIdx.x;
  const int wave = tid >> 6, lane = tid & 63;
  const int l15 = lane & 15, g = lane >> 4;
  const int nwg = gridDim.x * gridDim.y;
  const int wg0 = blockIdx.y * gridDim.x + blockIdx.x;
  const int wg = (wg0 & 7) * (nwg >> 3) + (wg0 >> 3);
  const int m0 = (wg / gridDim.x) * 128, n0 = (wg % gridDim.x) * 128;
  const int wr = wave >> 1, wc = wave & 1;

  f32x4 acc[4][4] = {};

  for (int k0 = 0; k0 < 1024; k0 += 64) {
    __syncthreads();
#pragma unroll
    for (int i = 0; i < 4; ++i) {
      const int gid = (i * 4 + wave) * 64 + lane;
      const int row = gid >> 3, gk = gid & 7;
      const int srcoff = k0 + ((gk ^ (row & 7)) << 3);
      gload16(A + (m0 + row) * 1024 + srcoff, As + (i * 4 + wave) * 512);
      gload16(B + (n0 + row) * 1024 + srcoff, Bs + (i * 4 + wave) * 512);
    }
    __syncthreads();
#pragma unroll
    for (int kc = 0; kc < 2; ++kc) {
      bf16x8 af[4], bfb[4];
#pragma unroll
      for (int mi = 0; mi < 4; ++mi) {
        const int row = wr * 64 + mi * 16 + l15;
        af[mi] = *(const bf16x8*)&As[row * 64 + (((kc * 4 + g) ^ (l15 & 7)) << 3)];
      }
#pragma unroll
      for (int ni = 0; ni < 4; ++ni) {
        const int row = wc * 64 + ni * 16 + l15;
        bfb[ni] = *(const bf16x8*)&Bs[row * 64 + (((kc * 4 + g) ^ (l15 & 7)) << 3)];
      }
#pragma unroll
      for (int mi = 0; mi < 4; ++mi)
#pragma unroll
        for (int ni = 0; ni < 4; ++ni)
          acc[mi][ni] = __builtin_amdgcn_mfma_f32_16x16x32_bf16(af[mi], bfb[ni], acc[mi][ni], 0, 0, 0);
    }
  }

  if (MODE == 0) {
#pragma unroll
    for (int mi = 0; mi < 4; ++mi) {
      const int mrow = m0 + wr * 64 + mi * 16 + g * 4;
#pragma unroll
      for (int r = 0; r < 4; ++r) {
        float* cp = Cout + (long)(mrow + r) * Ncols + n0 + wc * 64 + l15;
#pragma unroll
        for (int ni = 0; ni < 4; ++ni) cp[ni * 16] = acc[mi][ni][r];
      }
    }
  } else {
    const int blk_which = n0 >> 10;
    const int ncol = n0 + wc * 64;
    const int h = (ncol >> 6) & 15;

    if (blk_which == 2) {
#pragma unroll
      for (int mi = 0; mi < 4; ++mi) {
#pragma unroll
        for (int r = 0; r < 4; ++r) {
          float ss = 0.f;
#pragma unroll
          for (int ni = 0; ni < 4; ++ni) ss += acc[mi][ni][r] * acc[mi][ni][r];
          ss += __shfl_xor(ss, 1); ss += __shfl_xor(ss, 2);
          ss += __shfl_xor(ss, 4); ss += __shfl_xor(ss, 8);
          if (l15 == 0) {
            const int m = m0 + wr * 64 + mi * 16 + g * 4 + r;
            const int b = m >> 11, nseq = m & 2047;
            vninv[(b * 16 + h) * 2048 + nseq] = 1.0f / fmaxf(sqrtf(ss), 1e-12f);
          }
        }
      }
      __syncthreads();
#pragma unroll
      for (int mi = 0; mi < 4; ++mi)
#pragma unroll
        for (int ni = 0; ni < 4; ++ni) {
          bf16x4 v4;
#pragma unroll
          for (int r = 0; r < 4; ++r) v4[r] = (bf16)acc[mi][ni][r];
          *(bf16x4*)&shg.T[(wc * 64 + ni * 16 + l15) * 136 + wr * 64 + mi * 16 + g * 4] = v4;
        }
      __syncthreads();
      const int c = tid >> 1, half = tid & 1;
      const int gcol = n0 + c;
      const int hh = (gcol >> 6) & 15, d = gcol & 63;
      const int mb = m0 >> 11, nseq0 = m0 & 2047;
      bf16* dst = VtG + ((long)(mb * 16 + hh) * 64 + d) * 2048 + nseq0 + half * 64;
      const bf16* src = &shg.T[c * 136 + half * 64];
#pragma unroll
      for (int i = 0; i < 8; ++i)
        *(bf16x8*)(dst + i * 8) = *(const bf16x8*)(src + i * 8);
    } else {
      float scv[4][4];
#pragma unroll
      for (int mi = 0; mi < 4; ++mi) {
#pragma unroll
        for (int r = 0; r < 4; ++r) {
          float ss = 0.f;
#pragma unroll
          for (int ni = 0; ni < 4; ++ni) ss += acc[mi][ni][r] * acc[mi][ni][r];
          ss += __shfl_xor(ss, 1); ss += __shfl_xor(ss, 2);
          ss += __shfl_xor(ss, 4); ss += __shfl_xor(ss, 8);
          const float sc = rsqrtf(ss * (1.0f / 64) + RMS_EPS);
          scv[mi][r] = (blk_which == 0) ? sc * (0.125f * 1.44269504088896340736f) : sc;
        }
      }
      __syncthreads();
#pragma unroll
      for (int mi = 0; mi < 4; ++mi)
#pragma unroll
        for (int r = 0; r < 4; ++r) {
          const float sc = scv[mi][r];
#pragma unroll
          for (int ni = 0; ni < 4; ++ni)
            shg.T[(wr * 64 + mi * 16 + g * 4 + r) * 136 + wc * 64 + ni * 16 + l15] =
                (bf16)(acc[mi][ni][r] * sc);
        }
      __syncthreads();
      bf16* QK = (blk_which == 0) ? Qb : Kb;
      const int c8 = tid & 7, chh = (tid >> 3) & 1, r0 = tid >> 4;
      const int hh = ((n0 + chh * 64) >> 6) & 15;
#pragma unroll
      for (int p = 0; p < 8; ++p) {
        const int rr = r0 + p * 16;
        const int m = m0 + rr;
        const int bq = m >> 11, nseq = m & 2047;
        *(bf16x8*)(QK + ((long)(bq * 16 + hh) * 2048 + nseq) * 64 + c8 * 8) =
            *(const bf16x8*)&shg.T[rr * 136 + chh * 64 + c8 * 8];
      }
    }
  }
}

// ---------------- flash attention, 4 warps x 32x32 MFMA, swapped operands, KVBLK=128 ----
// R16-exact body and config (512 blocks x 256 threads, 2 blocks/CU) EXCEPT: no s_setprio.
__global__ __launch_bounds__(256, 2) void attn_kernel(
    const bf16* __restrict__ Qb, const bf16* __restrict__ Kb, const bf16* __restrict__ VtG,
    const float* __restrict__ vninv, bf16* __restrict__ Yb) {
  __shared__ bf16 Ks[2][128 * 64];  // [j][d] linear, swizzle key (j^(j>>3))&7
  __shared__ bf16 Vt[2][64 * 128];  // [d][j] linear, swizzle key (d^(d>>3))&7

  const int tid = threadIdx.x;
  const int wq = tid >> 6;
  const int lane = tid & 63;
  const int l31 = lane & 31, hi = lane >> 5;
  // XCD swizzle (512 blocks % 8 == 0 -> bijective)
  const int wg = (blockIdx.x & 7) * (gridDim.x >> 3) + (blockIdx.x >> 3);
  const int bh = wg >> 4, qb = wg & 15;
  const int b = bh >> 4, h = bh & 15;
  const long off = (long)bh * (2048 * 64);
  const bf16* Qp = Qb + off;
  const bf16* Kp = Kb + off;
  const bf16* VtP = VtG + (long)bh * 64 * 2048;
  const int qrow = qb * 128 + wq * 32 + l31;

  // Q B-frags in registers: row q=l31, k = kc*16 + hi*8 + i
  bf16x8 qf[4];
#pragma unroll
  for (int kc = 0; kc < 4; ++kc)
    qf[kc] = *(const bf16x8*)&Qp[qrow * 64 + kc * 16 + hi * 8];

  f32x16 o[2] = {};   // O^T[d][q]: q=l31, d = (r&3)+8*(r>>2)+4*hi+32*dt
  f32x16 lacc = {};   // per-slot P-sum accumulator; reduced once in epilogue
  f32x16 minit;       // loop-invariant -SMAX C-init for the first QK MFMA
#pragma unroll
  for (int r = 0; r < 16; ++r) minit[r] = -SMAX;

  // staging offsets (4 granules each for K and Vt per thread)
  int koff[4], voff[4];
#pragma unroll
  for (int i = 0; i < 4; ++i) {
    const int chunk = i * 4 + wq;
    const int j = chunk * 8 + (lane >> 3);
    koff[i] = j * 64 + (((lane & 7) ^ ((j ^ (j >> 3)) & 7)) << 3);
    const int d = chunk * 4 + (lane >> 4);
    voff[i] = d * 2048 + (((lane & 15) ^ ((d ^ (d >> 3)) & 7)) << 3);
  }

  // prologue: stage kv tile 0
#pragma unroll
  for (int i = 0; i < 4; ++i) {
    const int chunk = i * 4 + wq;
    gload16(Kp + koff[i], &Ks[0][chunk * 512]);
    gload16(VtP + voff[i], &Vt[0][chunk * 512]);
  }
  __syncthreads();

  int cur = 0;
  for (int it = 0; it < 16; ++it) {
    const int kv0 = it * 128;
    if (it < 15) {  // async prefetch next fat tile (T14)
#pragma unroll
      for (int i = 0; i < 4; ++i) {
        const int chunk = i * 4 + wq;
        gload16(Kp + (kv0 + 128) * 64 + koff[i], &Ks[cur ^ 1][chunk * 512]);
        gload16(VtP + (kv0 + 128) + voff[i], &Vt[cur ^ 1][chunk * 512]);
      }
    }
    const bf16* ks = &Ks[cur][0];
    const bf16* vt = &Vt[cur][0];

    // S^T - 12 = K * Q^T + (-12): first MFMA consumes the loop-invariant minit.
    f32x16 sv[4];
#pragma unroll
    for (int jt = 0; jt < 4; ++jt) {
      const int j = jt * 32 + l31;
      const int key = (j ^ (j >> 3)) & 7;
      {
        bf16x8 kf = *(const bf16x8*)&ks[j * 64 + ((hi ^ key) << 3)];
        sv[jt] = __builtin_amdgcn_mfma_f32_32x32x16_bf16(kf, qf[0], minit, 0, 0, 0);
      }
#pragma unroll
      for (int kc = 1; kc < 4; ++kc) {
        bf16x8 kf = *(const bf16x8*)&ks[j * 64 + (((2 * kc + hi) ^ key) << 3)];
        sv[jt] = __builtin_amdgcn_mfma_f32_32x32x16_bf16(kf, qf[kc], sv[jt], 0, 0, 0);
      }
    }

    // P = exp2(S' - 12); no max tracking needed (|S'| <= 11.54 by rms-norm bound)
#pragma unroll
    for (int jt = 0; jt < 4; ++jt)
#pragma unroll
      for (int r = 0; r < 16; ++r) sv[jt][r] = fexp2(sv[jt][r]);

    // row-sum accumulate only (reduction tree deferred to epilogue)
#pragma unroll
    for (int r = 0; r < 16; ++r)
      lacc[r] += (sv[0][r] + sv[1][r]) + (sv[2][r] + sv[3][r]);

    // ---- P (C-layout, q=lane) -> bf16 B-frags: pack + half-wave exchange ----
    u32 w[4][8];
#pragma unroll
    for (int jt = 0; jt < 4; ++jt)
#pragma unroll
      for (int i = 0; i < 8; ++i) w[jt][i] = pack2(sv[jt][2 * i], sv[jt][2 * i + 1]);
    bf16x8 pafr[8];  // B-frag kc: col q=l31, k-local i -> j = kc*16 + hi*8 + i
#pragma unroll
    for (int kc = 0; kc < 8; ++kc) {
      const int c = kc & 1, jt = kc >> 1;
      const u32 z1 = hi ? w[jt][4 * c + 0] : w[jt][4 * c + 2];
      const u32 z2 = hi ? w[jt][4 * c + 1] : w[jt][4 * c + 3];
      const u32 r1 = __shfl_xor(z1, 32);
      const u32 r2 = __shfl_xor(z2, 32);
      u32x4 pv;
      pv[0] = hi ? r1 : w[jt][4 * c + 0];
      pv[1] = hi ? r2 : w[jt][4 * c + 1];
      pv[2] = hi ? w[jt][4 * c + 2] : r1;
      pv[3] = hi ? w[jt][4 * c + 3] : r2;
      pafr[kc] = __builtin_bit_cast(bf16x8, pv);
    }

    // O^T += V^T * P : A = Vt rows (m=d), B = P (n=q); j-dim = 128
#pragma unroll
    for (int dt = 0; dt < 2; ++dt) {
      const int d = dt * 32 + l31;
      const int key = (d ^ (d >> 3)) & 7;
#pragma unroll
      for (int kc = 0; kc < 8; ++kc) {
        bf16x8 vf = *(const bf16x8*)&vt[d * 128 + (((2 * kc + hi) ^ key) << 3)];
        o[dt] = __builtin_amdgcn_mfma_f32_32x32x16_bf16(vf, pafr[kc], o[dt], 0, 0, 0);
      }
    }

    __syncthreads();
    cur ^= 1;
  }

  // one-time row-sum reduction: lrun = sum over 16 slots + cross-half
  float sm[16];
#pragma unroll
  for (int r = 0; r < 16; ++r) sm[r] = lacc[r];
#pragma unroll
  for (int s2 = 8; s2 > 0; s2 >>= 1)
#pragma unroll
    for (int r = 0; r < s2; ++r) sm[r] += sm[r + s2];
  const float lrun = sm[0] + __shfl_xor(sm[0], 32);

  // epilogue: y = O/l ; xsa: y -= (y . Vn) Vn ; store (B,N,C) bf16
  const float linv = 1.f / lrun;
  const float vni = vninv[bh * 2048 + qrow];
  const float cvn = vni * vni;
  const bf16* vq = VtP + qrow;
  float yv[2][16], vvf[2][16];
  float t = 0.f;
#pragma unroll
  for (int dt = 0; dt < 2; ++dt)
#pragma unroll
    for (int rr = 0; rr < 4; ++rr) {
#pragma unroll
      for (int e = 0; e < 4; ++e) {
        const int r = rr * 4 + e;  // d = e + 8*rr + 4*hi + 32*dt
        const int d = e + 8 * rr + 4 * hi + 32 * dt;
        const float y = o[dt][r] * linv;
        const float vx = (float)vq[d * 2048];
        yv[dt][r] = y; vvf[dt][r] = vx;
        t += y * vx;
      }
    }
  t += __shfl_xor(t, 32);
  const float coef = t * cvn;
  bf16* yp = Yb + ((long)b * 2048 + qrow) * 1024 + h * 64;
#pragma unroll
  for (int dt = 0; dt < 2; ++dt)
#pragma unroll
    for (int rr = 0; rr < 4; ++rr) {
      bf16x4 y4;
#pragma unroll
      for (int e = 0; e < 4; ++e) {
        const int r = rr * 4 + e;
        y4[e] = (bf16)(yv[dt][r] - coef * vvf[dt][r]);
      }
      *(bf16x4*)&yp[dt * 32 + rr * 8 + hi * 4] = y4;
    }
}

// ---------------- launch ----------------
extern "C" void kernel_launch(void* const* d_in, const int* in_sizes, int n_in,
                              void* d_out, int out_size, void* d_ws, size_t ws_size,
                              hipStream_t stream) {
  (void)in_sizes; (void)n_in; (void)out_size; (void)ws_size;
  const float* x = (const float*)d_in[0];
  const float* w_qkv = (const float*)d_in[1];
  const float* w_proj = (const float*)d_in[2];
  float* out = (float*)d_out;
  char* ws = (char*)d_ws;

  bf16* xb     = (bf16*)(ws);              //  8,388,608  x as bf16
  bf16* wqkvb  = (bf16*)(ws + 8388608);    //  6,291,456
  bf16* wprojb = (bf16*)(ws + 14680064);   //  2,097,152
  bf16* Qb     = (bf16*)(ws + 16777216);   //  8,388,608  rms-normed * 0.125*log2e
  bf16* Kb     = (bf16*)(ws + 25165824);   //  8,388,608  rms-normed
  bf16* VtG    = (bf16*)(ws + 33554432);   //  8,388,608  (B,H,D,N) V transposed
  float* vninv = (float*)(ws + 41943040);  //    524,288  1/max(||v||,1e-12)
  bf16* Yb     = (bf16*)(ws + 42467328);   //  8,388,608  (B,N,C) post-xsa

  cvt3_kernel<<<4096, 256, 0, stream>>>(x, w_qkv, w_proj, xb, wqkvb, wprojb);

  gemm_bt<1, 3><<<dim3(24, 32), 256, 0, stream>>>(xb, wqkvb, nullptr, 3072,
                                                  Qb, Kb, VtG, vninv);
  attn_kernel<<<512, 256, 0, stream>>>(Qb, Kb, VtG, vninv, Yb);
  gemm_bt<0, 2><<<dim3(8, 32), 256, 0, stream>>>(Yb, wprojb, out, 1024,
                                                 nullptr, nullptr, nullptr, nullptr);
}

// Round 21
// 122.334 us; speedup vs baseline: 1.3233x; 1.0059x over previous
//
#include <hip/hip_runtime.h>
#include <hip/hip_bf16.h>
#include <cstdint>

// Problem constants: B=2, N=2048, C=1024, H=16, D=64
// Q is stored pre-scaled by D^-0.5 * log2(e) so softmax runs in exp2 domain.
// V is materialized TRANSPOSED in global memory (VtG[bh][d][n]) by the QKV GEMM.
// STATIC-MAX softmax: rms_norm bounds |S'| <= 8*log2e = 11.54 < 12 -> P = exp2(S'-12).
// R21: ZERO-SHUFFLE PV. MFMA is invariant under a fixed permutation pi of the 16 k-slots
// applied to BOTH operands. pi = {0,1,2,3,8,9,10,11 | 4,5,6,7,12,13,14,15} makes each
// lane's OWN packed P-words the correct B-frag (no cross-lane exchange), with the V^T
// A-frag read as two b64 runs (j = 16kc+4hi and 16kc+8+4hi) instead of one b128.
#define RMS_EPS 1.1920928955078125e-07f
#define SMAX 12.0f

typedef __bf16 bf16;
typedef __attribute__((ext_vector_type(8))) __bf16 bf16x8;
typedef __attribute__((ext_vector_type(4))) __bf16 bf16x4;
typedef __attribute__((ext_vector_type(4))) float f32x4;
typedef __attribute__((ext_vector_type(16))) float f32x16;
typedef unsigned int u32;
typedef __attribute__((ext_vector_type(2))) u32 u32x2;
typedef __attribute__((ext_vector_type(4))) u32 u32x4;

__device__ __forceinline__ void gload16(const bf16* g, bf16* l) {
  __builtin_amdgcn_global_load_lds(
      (__attribute__((address_space(1))) void*)(g),
      (__attribute__((address_space(3))) void*)(l), 16, 0, 0);
}

__device__ __forceinline__ float fexp2(float x) {
#if __has_builtin(__builtin_amdgcn_exp2f)
  return __builtin_amdgcn_exp2f(x);
#else
  return exp2f(x);
#endif
}

__device__ __forceinline__ u32 pack2(float a, float b) {
  unsigned short xa = __builtin_bit_cast(unsigned short, (bf16)a);
  unsigned short xb = __builtin_bit_cast(unsigned short, (bf16)b);
  return (u32)xa | ((u32)xb << 16);
}

// ---------------- fused f32 -> bf16 convert for all three inputs ----------------
__global__ __launch_bounds__(256) void cvt3_kernel(
    const float* __restrict__ x, const float* __restrict__ wq, const float* __restrict__ wp,
    bf16* __restrict__ xo, bf16* __restrict__ wqo, bf16* __restrict__ wpo) {
  int i = blockIdx.x * 256 + threadIdx.x;
  const float* s; bf16* d; int off;
  if (i < 524288) { s = x; d = xo; off = i; }
  else if (i < 917504) { s = wq; d = wqo; off = i - 524288; }
  else { s = wp; d = wpo; off = i - 917504; }
  const float4* s4 = (const float4*)s;
  float4 a = s4[off * 2], b = s4[off * 2 + 1];
  bf16x8 o;
  o[0] = (bf16)a.x; o[1] = (bf16)a.y; o[2] = (bf16)a.z; o[3] = (bf16)a.w;
  o[4] = (bf16)b.x; o[5] = (bf16)b.y; o[6] = (bf16)b.z; o[7] = (bf16)b.w;
  *(bf16x8*)(d + off * 8) = o;
}

// ---------------- GEMM C = A * B^T (R16, proven) ----------------
template <int MODE, int MINW>
__global__ __launch_bounds__(256, MINW) void gemm_bt(
    const bf16* __restrict__ A, const bf16* __restrict__ B,
    float* __restrict__ Cout, int Ncols,
    bf16* __restrict__ Qb, bf16* __restrict__ Kb, bf16* __restrict__ VtG,
    float* __restrict__ vninv) {
  union ShG {
    struct { bf16 As[128 * 64]; bf16 Bs[128 * 64]; } s;
    bf16 T[128 * 136];
  };
  __shared__ ShG shg;
  bf16* As = shg.s.As;
  bf16* Bs = shg.s.Bs;

  const int tid = threadIdx.x;
  const int wave = tid >> 6, lane = tid & 63;
  const int l15 = lane & 15, g = lane >> 4;
  const int nwg = gridDim.x * gridDim.y;
  const int wg0 = blockIdx.y * gridDim.x + blockIdx.x;
  const int wg = (wg0 & 7) * (nwg >> 3) + (wg0 >> 3);
  const int m0 = (wg / gridDim.x) * 128, n0 = (wg % gridDim.x) * 128;
  const int wr = wave >> 1, wc = wave & 1;

  f32x4 acc[4][4] = {};

  for (int k0 = 0; k0 < 1024; k0 += 64) {
    __syncthreads();
#pragma unroll
    for (int i = 0; i < 4; ++i) {
      const int gid = (i * 4 + wave) * 64 + lane;
      const int row = gid >> 3, gk = gid & 7;
      const int srcoff = k0 + ((gk ^ (row & 7)) << 3);
      gload16(A + (m0 + row) * 1024 + srcoff, As + (i * 4 + wave) * 512);
      gload16(B + (n0 + row) * 1024 + srcoff, Bs + (i * 4 + wave) * 512);
    }
    __syncthreads();
#pragma unroll
    for (int kc = 0; kc < 2; ++kc) {
      bf16x8 af[4], bfb[4];
#pragma unroll
      for (int mi = 0; mi < 4; ++mi) {
        const int row = wr * 64 + mi * 16 + l15;
        af[mi] = *(const bf16x8*)&As[row * 64 + (((kc * 4 + g) ^ (l15 & 7)) << 3)];
      }
#pragma unroll
      for (int ni = 0; ni < 4; ++ni) {
        const int row = wc * 64 + ni * 16 + l15;
        bfb[ni] = *(const bf16x8*)&Bs[row * 64 + (((kc * 4 + g) ^ (l15 & 7)) << 3)];
      }
#pragma unroll
      for (int mi = 0; mi < 4; ++mi)
#pragma unroll
        for (int ni = 0; ni < 4; ++ni)
          acc[mi][ni] = __builtin_amdgcn_mfma_f32_16x16x32_bf16(af[mi], bfb[ni], acc[mi][ni], 0, 0, 0);
    }
  }

  if (MODE == 0) {
#pragma unroll
    for (int mi = 0; mi < 4; ++mi) {
      const int mrow = m0 + wr * 64 + mi * 16 + g * 4;
#pragma unroll
      for (int r = 0; r < 4; ++r) {
        float* cp = Cout + (long)(mrow + r) * Ncols + n0 + wc * 64 + l15;
#pragma unroll
        for (int ni = 0; ni < 4; ++ni) cp[ni * 16] = acc[mi][ni][r];
      }
    }
  } else {
    const int blk_which = n0 >> 10;
    const int ncol = n0 + wc * 64;
    const int h = (ncol >> 6) & 15;

    if (blk_which == 2) {
#pragma unroll
      for (int mi = 0; mi < 4; ++mi) {
#pragma unroll
        for (int r = 0; r < 4; ++r) {
          float ss = 0.f;
#pragma unroll
          for (int ni = 0; ni < 4; ++ni) ss += acc[mi][ni][r] * acc[mi][ni][r];
          ss += __shfl_xor(ss, 1); ss += __shfl_xor(ss, 2);
          ss += __shfl_xor(ss, 4); ss += __shfl_xor(ss, 8);
          if (l15 == 0) {
            const int m = m0 + wr * 64 + mi * 16 + g * 4 + r;
            const int b = m >> 11, nseq = m & 2047;
            vninv[(b * 16 + h) * 2048 + nseq] = 1.0f / fmaxf(sqrtf(ss), 1e-12f);
          }
        }
      }
      __syncthreads();
#pragma unroll
      for (int mi = 0; mi < 4; ++mi)
#pragma unroll
        for (int ni = 0; ni < 4; ++ni) {
          bf16x4 v4;
#pragma unroll
          for (int r = 0; r < 4; ++r) v4[r] = (bf16)acc[mi][ni][r];
          *(bf16x4*)&shg.T[(wc * 64 + ni * 16 + l15) * 136 + wr * 64 + mi * 16 + g * 4] = v4;
        }
      __syncthreads();
      const int c = tid >> 1, half = tid & 1;
      const int gcol = n0 + c;
      const int hh = (gcol >> 6) & 15, d = gcol & 63;
      const int mb = m0 >> 11, nseq0 = m0 & 2047;
      bf16* dst = VtG + ((long)(mb * 16 + hh) * 64 + d) * 2048 + nseq0 + half * 64;
      const bf16* src = &shg.T[c * 136 + half * 64];
#pragma unroll
      for (int i = 0; i < 8; ++i)
        *(bf16x8*)(dst + i * 8) = *(const bf16x8*)(src + i * 8);
    } else {
      float scv[4][4];
#pragma unroll
      for (int mi = 0; mi < 4; ++mi) {
#pragma unroll
        for (int r = 0; r < 4; ++r) {
          float ss = 0.f;
#pragma unroll
          for (int ni = 0; ni < 4; ++ni) ss += acc[mi][ni][r] * acc[mi][ni][r];
          ss += __shfl_xor(ss, 1); ss += __shfl_xor(ss, 2);
          ss += __shfl_xor(ss, 4); ss += __shfl_xor(ss, 8);
          const float sc = rsqrtf(ss * (1.0f / 64) + RMS_EPS);
          scv[mi][r] = (blk_which == 0) ? sc * (0.125f * 1.44269504088896340736f) : sc;
        }
      }
      __syncthreads();
#pragma unroll
      for (int mi = 0; mi < 4; ++mi)
#pragma unroll
        for (int r = 0; r < 4; ++r) {
          const float sc = scv[mi][r];
#pragma unroll
          for (int ni = 0; ni < 4; ++ni)
            shg.T[(wr * 64 + mi * 16 + g * 4 + r) * 136 + wc * 64 + ni * 16 + l15] =
                (bf16)(acc[mi][ni][r] * sc);
        }
      __syncthreads();
      bf16* QK = (blk_which == 0) ? Qb : Kb;
      const int c8 = tid & 7, chh = (tid >> 3) & 1, r0 = tid >> 4;
      const int hh = ((n0 + chh * 64) >> 6) & 15;
#pragma unroll
      for (int p = 0; p < 8; ++p) {
        const int rr = r0 + p * 16;
        const int m = m0 + rr;
        const int bq = m >> 11, nseq = m & 2047;
        *(bf16x8*)(QK + ((long)(bq * 16 + hh) * 2048 + nseq) * 64 + c8 * 8) =
            *(const bf16x8*)&shg.T[rr * 136 + chh * 64 + c8 * 8];
      }
    }
  }
}

// ---------------- flash attention, 4 warps x 32x32 MFMA, swapped operands, KVBLK=128 ----
// R20 config (512 blocks x 256 threads, 2 blocks/CU), ZERO-SHUFFLE PV (k-slot perm pi).
__global__ __launch_bounds__(256, 2) void attn_kernel(
    const bf16* __restrict__ Qb, const bf16* __restrict__ Kb, const bf16* __restrict__ VtG,
    const float* __restrict__ vninv, bf16* __restrict__ Yb) {
  __shared__ bf16 Ks[2][128 * 64];  // [j][d] linear, swizzle key (j^(j>>3))&7
  __shared__ bf16 Vt[2][64 * 128];  // [d][j] linear, swizzle key (d^(d>>3))&7

  const int tid = threadIdx.x;
  const int wq = tid >> 6;
  const int lane = tid & 63;
  const int l31 = lane & 31, hi = lane >> 5;
  // XCD swizzle (512 blocks % 8 == 0 -> bijective)
  const int wg = (blockIdx.x & 7) * (gridDim.x >> 3) + (blockIdx.x >> 3);
  const int bh = wg >> 4, qb = wg & 15;
  const int b = bh >> 4, h = bh & 15;
  const long off = (long)bh * (2048 * 64);
  const bf16* Qp = Qb + off;
  const bf16* Kp = Kb + off;
  const bf16* VtP = VtG + (long)bh * 64 * 2048;
  const int qrow = qb * 128 + wq * 32 + l31;

  // Q B-frags in registers: row q=l31, k = kc*16 + hi*8 + i
  bf16x8 qf[4];
#pragma unroll
  for (int kc = 0; kc < 4; ++kc)
    qf[kc] = *(const bf16x8*)&Qp[qrow * 64 + kc * 16 + hi * 8];

  f32x16 o[2] = {};   // O^T[d][q]: q=l31, d = (r&3)+8*(r>>2)+4*hi+32*dt
  f32x16 lacc = {};   // per-slot P-sum accumulator; reduced once in epilogue
  f32x16 minit;       // loop-invariant -SMAX C-init for the first QK MFMA
#pragma unroll
  for (int r = 0; r < 16; ++r) minit[r] = -SMAX;

  // staging offsets (4 granules each for K and Vt per thread)
  int koff[4], voff[4];
#pragma unroll
  for (int i = 0; i < 4; ++i) {
    const int chunk = i * 4 + wq;
    const int j = chunk * 8 + (lane >> 3);
    koff[i] = j * 64 + (((lane & 7) ^ ((j ^ (j >> 3)) & 7)) << 3);
    const int d = chunk * 4 + (lane >> 4);
    voff[i] = d * 2048 + (((lane & 15) ^ ((d ^ (d >> 3)) & 7)) << 3);
  }

  // prologue: stage kv tile 0
#pragma unroll
  for (int i = 0; i < 4; ++i) {
    const int chunk = i * 4 + wq;
    gload16(Kp + koff[i], &Ks[0][chunk * 512]);
    gload16(VtP + voff[i], &Vt[0][chunk * 512]);
  }
  __syncthreads();

  int cur = 0;
  for (int it = 0; it < 16; ++it) {
    const int kv0 = it * 128;
    if (it < 15) {  // async prefetch next fat tile (T14)
#pragma unroll
      for (int i = 0; i < 4; ++i) {
        const int chunk = i * 4 + wq;
        gload16(Kp + (kv0 + 128) * 64 + koff[i], &Ks[cur ^ 1][chunk * 512]);
        gload16(VtP + (kv0 + 128) + voff[i], &Vt[cur ^ 1][chunk * 512]);
      }
    }
    const bf16* ks = &Ks[cur][0];
    const bf16* vt = &Vt[cur][0];

    // S^T - 12 = K * Q^T + (-12): first MFMA consumes the loop-invariant minit.
    f32x16 sv[4];
#pragma unroll
    for (int jt = 0; jt < 4; ++jt) {
      const int j = jt * 32 + l31;
      const int key = (j ^ (j >> 3)) & 7;
      {
        bf16x8 kf = *(const bf16x8*)&ks[j * 64 + ((hi ^ key) << 3)];
        sv[jt] = __builtin_amdgcn_mfma_f32_32x32x16_bf16(kf, qf[0], minit, 0, 0, 0);
      }
#pragma unroll
      for (int kc = 1; kc < 4; ++kc) {
        bf16x8 kf = *(const bf16x8*)&ks[j * 64 + (((2 * kc + hi) ^ key) << 3)];
        sv[jt] = __builtin_amdgcn_mfma_f32_32x32x16_bf16(kf, qf[kc], sv[jt], 0, 0, 0);
      }
    }

    // P = exp2(S' - 12); no max tracking needed (|S'| <= 11.54 by rms-norm bound)
#pragma unroll
    for (int jt = 0; jt < 4; ++jt)
#pragma unroll
      for (int r = 0; r < 16; ++r) sv[jt][r] = fexp2(sv[jt][r]);

    // row-sum accumulate only (reduction tree deferred to epilogue)
#pragma unroll
    for (int r = 0; r < 16; ++r)
      lacc[r] += (sv[0][r] + sv[1][r]) + (sv[2][r] + sv[3][r]);

    // ---- P -> B-frags with ZERO exchange (k-slot permutation pi) ----
    // w[jt][2*rr+c2] covers j = jt*32 + 8*rr + 4*hi + 2*c2 + {0,1}; under pi each
    // lane's own 4 words ARE the B-frag for both halves.
    u32 w[4][8];
#pragma unroll
    for (int jt = 0; jt < 4; ++jt)
#pragma unroll
      for (int i = 0; i < 8; ++i) w[jt][i] = pack2(sv[jt][2 * i], sv[jt][2 * i + 1]);
    bf16x8 pafr[8];
#pragma unroll
    for (int kc = 0; kc < 8; ++kc) {
      const int c = kc & 1, jt = kc >> 1;
      u32x4 pv;
      pv[0] = w[jt][4 * c + 0];
      pv[1] = w[jt][4 * c + 1];
      pv[2] = w[jt][4 * c + 2];
      pv[3] = w[jt][4 * c + 3];
      pafr[kc] = __builtin_bit_cast(bf16x8, pv);
    }

    // O^T += V^T * P with pi-permuted A-frag: slot k of lane (d,hi) holds
    // V^T[d][16kc + pi(hi*8+i)] -> two b64 runs at j = 16kc+4hi and 16kc+8+4hi.
#pragma unroll
    for (int dt = 0; dt < 2; ++dt) {
      const int d = dt * 32 + l31;
      const int key = (d ^ (d >> 3)) & 7;
#pragma unroll
      for (int kc = 0; kc < 8; ++kc) {
        const u32x2 lo64 = *(const u32x2*)&vt[d * 128 + (((2 * kc) ^ key) << 3) + 4 * hi];
        const u32x2 hi64 = *(const u32x2*)&vt[d * 128 + (((2 * kc + 1) ^ key) << 3) + 4 * hi];
        u32x4 q;
        q[0] = lo64[0]; q[1] = lo64[1]; q[2] = hi64[0]; q[3] = hi64[1];
        const bf16x8 vf = __builtin_bit_cast(bf16x8, q);
        o[dt] = __builtin_amdgcn_mfma_f32_32x32x16_bf16(vf, pafr[kc], o[dt], 0, 0, 0);
      }
    }

    __syncthreads();
    cur ^= 1;
  }

  // one-time row-sum reduction: lrun = sum over 16 slots + cross-half
  float sm[16];
#pragma unroll
  for (int r = 0; r < 16; ++r) sm[r] = lacc[r];
#pragma unroll
  for (int s2 = 8; s2 > 0; s2 >>= 1)
#pragma unroll
    for (int r = 0; r < s2; ++r) sm[r] += sm[r + s2];
  const float lrun = sm[0] + __shfl_xor(sm[0], 32);

  // epilogue: y = O/l ; xsa: y -= (y . Vn) Vn ; store (B,N,C) bf16
  const float linv = 1.f / lrun;
  const float vni = vninv[bh * 2048 + qrow];
  const float cvn = vni * vni;
  const bf16* vq = VtP + qrow;
  float yv[2][16], vvf[2][16];
  float t = 0.f;
#pragma unroll
  for (int dt = 0; dt < 2; ++dt)
#pragma unroll
    for (int rr = 0; rr < 4; ++rr) {
#pragma unroll
      for (int e = 0; e < 4; ++e) {
        const int r = rr * 4 + e;  // d = e + 8*rr + 4*hi + 32*dt
        const int d = e + 8 * rr + 4 * hi + 32 * dt;
        const float y = o[dt][r] * linv;
        const float vx = (float)vq[d * 2048];
        yv[dt][r] = y; vvf[dt][r] = vx;
        t += y * vx;
      }
    }
  t += __shfl_xor(t, 32);
  const float coef = t * cvn;
  bf16* yp = Yb + ((long)b * 2048 + qrow) * 1024 + h * 64;
#pragma unroll
  for (int dt = 0; dt < 2; ++dt)
#pragma unroll
    for (int rr = 0; rr < 4; ++rr) {
      bf16x4 y4;
#pragma unroll
      for (int e = 0; e < 4; ++e) {
        const int r = rr * 4 + e;
        y4[e] = (bf16)(yv[dt][r] - coef * vvf[dt][r]);
      }
      *(bf16x4*)&yp[dt * 32 + rr * 8 + hi * 4] = y4;
    }
}

// ---------------- launch ----------------
extern "C" void kernel_launch(void* const* d_in, const int* in_sizes, int n_in,
                              void* d_out, int out_size, void* d_ws, size_t ws_size,
                              hipStream_t stream) {
  (void)in_sizes; (void)n_in; (void)out_size; (void)ws_size;
  const float* x = (const float*)d_in[0];
  const float* w_qkv = (const float*)d_in[1];
  const float* w_proj = (const float*)d_in[2];
  float* out = (float*)d_out;
  char* ws = (char*)d_ws;

  bf16* xb     = (bf16*)(ws);              //  8,388,608  x as bf16
  bf16* wqkvb  = (bf16*)(ws + 8388608);    //  6,291,456
  bf16* wprojb = (bf16*)(ws + 14680064);   //  2,097,152
  bf16* Qb     = (bf16*)(ws + 16777216);   //  8,388,608  rms-normed * 0.125*log2e
  bf16* Kb     = (bf16*)(ws + 25165824);   //  8,388,608  rms-normed
  bf16* VtG    = (bf16*)(ws + 33554432);   //  8,388,608  (B,H,D,N) V transposed
  float* vninv = (float*)(ws + 41943040);  //    524,288  1/max(||v||,1e-12)
  bf16* Yb     = (bf16*)(ws + 42467328);   //  8,388,608  (B,N,C) post-xsa

  cvt3_kernel<<<4096, 256, 0, stream>>>(x, w_qkv, w_proj, xb, wqkvb, wprojb);

  gemm_bt<1, 3><<<dim3(24, 32), 256, 0, stream>>>(xb, wqkvb, nullptr, 3072,
                                                  Qb, Kb, VtG, vninv);
  attn_kernel<<<512, 256, 0, stream>>>(Qb, Kb, VtG, vninv, Yb);
  gemm_bt<0, 2><<<dim3(8, 32), 256, 0, stream>>>(Yb, wprojb, out, 1024,
                                                 nullptr, nullptr, nullptr, nullptr);
}